// Round 1
// baseline (331.165 us; speedup 1.0000x reference)
//
#include <hip/hip_runtime.h>

// ShrdMHAttention on MI355X (gfx950).
// Pipeline: cvt/transpose -> bf16 MFMA proj GEMM (+RoPE epilogue) -> causal
// flash attention -> output GEMM. All MFMA = v_mfma_f32_16x16x32_bf16.
// Workspace layout (needs 65 MB):
//   0MB xb(S,D) | 8MB qbT(H,128,D) [reused as z(S,2048) after proj] |
//   16MB kbT | 24MB vbT | 32MB obT(2048,2048) | 40MB rq(H,S,128) |
//   48MB rk | 56MB vst(H,128,S) | 64MB sin/cos tables (1MB)

#define S_LEN   2048
#define D_MODEL 2048
#define NHEAD   16
#define DHEAD   128

using f32x4  = __attribute__((ext_vector_type(4))) float;
using bf16x8 = __attribute__((ext_vector_type(8))) __bf16;

__device__ __forceinline__ unsigned short f2bf(float f) {
  unsigned int u = __builtin_bit_cast(unsigned int, f);
  u += 0x7fffu + ((u >> 16) & 1u);          // RNE
  return (unsigned short)(u >> 16);
}

// ---------- fp32 -> bf16 copy (x) ----------
__global__ void k_cvt(const float* __restrict__ in, unsigned short* __restrict__ out) {
  int i = (blockIdx.x * 256 + threadIdx.x) * 4;
  float4 v = *reinterpret_cast<const float4*>(in + i);
  ushort4 o; o.x = f2bf(v.x); o.y = f2bf(v.y); o.z = f2bf(v.z); o.w = f2bf(v.w);
  *reinterpret_cast<ushort4*>(out + i) = o;
}

// ---------- RoPE sin/cos tables: rot = s * (theta * (-c/64)), accurate sincos ----------
__global__ void k_tab(const float* __restrict__ theta_p, float* __restrict__ sint,
                      float* __restrict__ cost) {
  int i = blockIdx.x * 256 + threadIdx.x;   // [0, 2048*64)
  int s = i >> 6, c = i & 63;
  float rate = theta_p[0] * (-(float)c / 64.0f);   // match reference rounding order
  float sn, cs;
  sincosf((float)s * rate, &sn, &cs);
  sint[i] = sn; cost[i] = cs;
}

// ---------- transpose+convert: fp32 (B,R,C) -> bf16 (B,C,R) ----------
__global__ void k_tr(const float* __restrict__ in, unsigned short* __restrict__ out,
                     int R, int C) {
  __shared__ float t[32][33];
  int b = blockIdx.x, rt = blockIdx.y, ct = blockIdx.z;
  const float* ip = in + (size_t)b * R * C;
  unsigned short* op = out + (size_t)b * R * C;
  int tx = threadIdx.x & 31, ty = threadIdx.x >> 5;   // 32 x 8
  #pragma unroll
  for (int i = 0; i < 4; i++)
    t[ty + i * 8][tx] = ip[(size_t)(rt * 32 + ty + i * 8) * C + ct * 32 + tx];
  __syncthreads();
  #pragma unroll
  for (int i = 0; i < 4; i++)
    op[(size_t)(ct * 32 + ty + i * 8) * R + rt * 32 + tx] = f2bf(t[tx][ty + i * 8]);
}

// ---------- projection GEMM: C(128 x 128) = x-tile @ W_h^T, epilogue rope/scale ----------
// grid (16 s-tiles, 16 heads, 3 {q,k,v}); 4 waves, each wave = 32 rows x 128 cols
__global__ __launch_bounds__(256) void k_proj(
    const unsigned short* __restrict__ xb,
    const unsigned short* __restrict__ wq, const unsigned short* __restrict__ wk,
    const unsigned short* __restrict__ wv,
    const float* __restrict__ sint, const float* __restrict__ cost,
    unsigned short* __restrict__ rq, unsigned short* __restrict__ rk,
    unsigned short* __restrict__ vst) {
  __shared__ uint4 ldsbuf[2048];            // 32 KB: A[128][64] + B[128][64] bf16, swizzled
  char* lds = (char*)ldsbuf;
  const int tid = threadIdx.x, l = tid & 63, w = tid >> 6;
  const int lr = l & 15, lk = l >> 4;
  const int s0 = blockIdx.x * 128;
  const int h = blockIdx.y, which = blockIdx.z;
  const unsigned short* wsel = which == 0 ? wq : (which == 1 ? wk : wv);
  const unsigned short* wbase = wsel + (size_t)h * DHEAD * D_MODEL;

  f32x4 acc[2][8] = {};

  for (int kt = 0; kt < D_MODEL; kt += 64) {
    #pragma unroll
    for (int j = 0; j < 4; j++) {           // stage 2x16KB, XOR-swizzled chunks
      int ci = tid + j * 256;
      int r = ci >> 3, c16 = ci & 7;
      int sw = (c16 ^ (r & 7)) * 16;
      bf16x8 av = *reinterpret_cast<const bf16x8*>(xb + (size_t)(s0 + r) * D_MODEL + kt + c16 * 8);
      *reinterpret_cast<bf16x8*>(lds + r * 128 + sw) = av;
      bf16x8 bv = *reinterpret_cast<const bf16x8*>(wbase + (size_t)r * D_MODEL + kt + c16 * 8);
      *reinterpret_cast<bf16x8*>(lds + 16384 + r * 128 + sw) = bv;
    }
    __syncthreads();
    #pragma unroll
    for (int kk = 0; kk < 2; kk++) {
      const int kb = kk * 64 + lk * 16;
      bf16x8 a[2], b[8];
      #pragma unroll
      for (int mf = 0; mf < 2; mf++) {
        int rr = w * 32 + mf * 16 + lr;
        a[mf] = *reinterpret_cast<const bf16x8*>(lds + rr * 128 + (kb ^ ((rr & 7) << 4)));
      }
      #pragma unroll
      for (int nf = 0; nf < 8; nf++) {
        int rn = nf * 16 + lr;
        b[nf] = *reinterpret_cast<const bf16x8*>(lds + 16384 + rn * 128 + (kb ^ ((rn & 7) << 4)));
      }
      #pragma unroll
      for (int mf = 0; mf < 2; mf++)
        #pragma unroll
        for (int nf = 0; nf < 8; nf++)
          acc[mf][nf] = __builtin_amdgcn_mfma_f32_16x16x32_bf16(a[mf], b[nf], acc[mf][nf], 0, 0, 0);
    }
    __syncthreads();
  }

  const float xscale = 0.022097086912079608f;   // 1/sqrt(2048)
  if (which < 2) {
    unsigned short* dst = (which == 0 ? rq : rk) + (size_t)h * S_LEN * DHEAD;
    #pragma unroll
    for (int mf = 0; mf < 2; mf++) {
      #pragma unroll
      for (int nf = 0; nf < 4; nf++) {
        int c1 = nf * 16 + lr;                  // 0..63; pair (c1, c1+64) in this thread
        #pragma unroll
        for (int rg = 0; rg < 4; rg++) {
          int srow = s0 + w * 32 + mf * 16 + lk * 4 + rg;
          float sn = sint[srow * 64 + c1], cs = cost[srow * 64 + c1];
          float x1 = acc[mf][nf][rg] * xscale;
          float x2 = acc[mf][nf + 4][rg] * xscale;
          dst[(size_t)srow * DHEAD + c1]      = f2bf(cs * x1 - sn * x2);
          dst[(size_t)srow * DHEAD + c1 + 64] = f2bf(sn * x1 + cs * x2);
        }
      }
    }
  } else {                                      // v: store transposed vst[h][c][s]
    unsigned short* dst = vst + (size_t)h * DHEAD * S_LEN;
    #pragma unroll
    for (int mf = 0; mf < 2; mf++) {
      int rbase = s0 + w * 32 + mf * 16 + lk * 4;
      #pragma unroll
      for (int nf = 0; nf < 8; nf++) {
        int c = nf * 16 + lr;
        ushort4 ov;
        ov.x = f2bf(acc[mf][nf][0] * xscale); ov.y = f2bf(acc[mf][nf][1] * xscale);
        ov.z = f2bf(acc[mf][nf][2] * xscale); ov.w = f2bf(acc[mf][nf][3] * xscale);
        *reinterpret_cast<ushort4*>(dst + (size_t)c * S_LEN + rbase) = ov;
      }
    }
  }
}

// ---------- causal flash attention ----------
// grid 256 = (head, q-tile of 128 rows); 4 waves x 32 q-rows; KV tiles of 32
__global__ __launch_bounds__(256) void k_attn(
    const unsigned short* __restrict__ rq, const unsigned short* __restrict__ rk,
    const unsigned short* __restrict__ vst, unsigned short* __restrict__ z) {
  __shared__ uint4 ldsbuf[1536];            // 24KB: K[32][128] | Vt[128][32] | P[4][32][32]
  char* lds = (char*)ldsbuf;
  const int tid = threadIdx.x, l = tid & 63, w = tid >> 6;
  const int lr = l & 15, lk = l >> 4;
  const int h = blockIdx.x >> 4, qt = blockIdx.x & 15;
  const int s0 = qt * 128;
  const float ascale = 0.08838834764831845f;    // 1/sqrt(128)

  bf16x8 aq[2][4];
  #pragma unroll
  for (int mf = 0; mf < 2; mf++)
    #pragma unroll
    for (int kk = 0; kk < 4; kk++)
      aq[mf][kk] = *reinterpret_cast<const bf16x8*>(
          rq + (size_t)h * S_LEN * DHEAD + (size_t)(s0 + w * 32 + mf * 16 + lr) * DHEAD + kk * 32 + lk * 8);

  f32x4 O[2][8] = {};
  float m_st[2][4], l_st[2][4];
  #pragma unroll
  for (int mf = 0; mf < 2; mf++)
    #pragma unroll
    for (int rg = 0; rg < 4; rg++) { m_st[mf][rg] = -3.0e38f; l_st[mf][rg] = 0.0f; }

  const int wlast = s0 + w * 32 + 31;
  const int nt = (s0 + 128) / 32;
  for (int it = 0; it < nt; it++) {
    const int t0 = it * 32;
    #pragma unroll
    for (int j = 0; j < 2; j++) {           // stage K[32][128], swz r&7
      int ci = tid + j * 256;
      int r = ci >> 4, c16 = ci & 15;
      bf16x8 v = *reinterpret_cast<const bf16x8*>(
          rk + (size_t)h * S_LEN * DHEAD + (size_t)(t0 + r) * DHEAD + c16 * 8);
      *reinterpret_cast<bf16x8*>(lds + r * 256 + ((c16 ^ (r & 7)) * 16)) = v;
    }
    #pragma unroll
    for (int j = 0; j < 2; j++) {           // stage Vt[128][32], swz r&3
      int ci = tid + j * 256;
      int r = ci >> 2, c16 = ci & 3;
      bf16x8 v = *reinterpret_cast<const bf16x8*>(
          vst + (size_t)h * DHEAD * S_LEN + (size_t)r * S_LEN + t0 + (c16 ^ (r & 3)) * 8);
      *reinterpret_cast<bf16x8*>(lds + 8192 + r * 64 + c16 * 16) = v;
    }
    __syncthreads();
    if (t0 <= wlast) {
      f32x4 sc[2][2] = {};
      #pragma unroll
      for (int kk = 0; kk < 4; kk++) {      // QK^T
        const int kb = kk * 64 + lk * 16;
        bf16x8 bk[2];
        #pragma unroll
        for (int nf = 0; nf < 2; nf++) {
          int rn = nf * 16 + lr;
          bk[nf] = *reinterpret_cast<const bf16x8*>(lds + rn * 256 + (kb ^ ((rn & 7) << 4)));
        }
        #pragma unroll
        for (int mf = 0; mf < 2; mf++)
          #pragma unroll
          for (int nf = 0; nf < 2; nf++)
            sc[mf][nf] = __builtin_amdgcn_mfma_f32_16x16x32_bf16(aq[mf][kk], bk[nf], sc[mf][nf], 0, 0, 0);
      }
      #pragma unroll
      for (int mf = 0; mf < 2; mf++) {      // scale + causal mask + online softmax
        float pmax[4];
        #pragma unroll
        for (int rg = 0; rg < 4; rg++) {
          int srow = s0 + w * 32 + mf * 16 + lk * 4 + rg;
          float v0 = sc[mf][0][rg] * ascale;
          float v1 = sc[mf][1][rg] * ascale;
          if (t0 + lr > srow)      v0 = -1.0e9f;
          if (t0 + 16 + lr > srow) v1 = -1.0e9f;
          sc[mf][0][rg] = v0; sc[mf][1][rg] = v1;
          float mx = fmaxf(v0, v1);
          #pragma unroll
          for (int d = 1; d < 16; d <<= 1) mx = fmaxf(mx, __shfl_xor(mx, d, 64));
          pmax[rg] = mx;
        }
        #pragma unroll
        for (int rg = 0; rg < 4; rg++) {
          float mo = m_st[mf][rg];
          float mn = fmaxf(mo, pmax[rg]);
          float sf = __expf(mo - mn);
          m_st[mf][rg] = mn;
          float p0 = __expf(sc[mf][0][rg] - mn);
          float p1 = __expf(sc[mf][1][rg] - mn);
          sc[mf][0][rg] = p0; sc[mf][1][rg] = p1;
          float rs = p0 + p1;
          #pragma unroll
          for (int d = 1; d < 16; d <<= 1) rs += __shfl_xor(rs, d, 64);
          l_st[mf][rg] = l_st[mf][rg] * sf + rs;
          #pragma unroll
          for (int vf = 0; vf < 8; vf++) O[mf][vf][rg] *= sf;
        }
      }
      #pragma unroll
      for (int mf = 0; mf < 2; mf++)        // P -> per-wave LDS (C-layout -> A-layout)
        #pragma unroll
        for (int nf = 0; nf < 2; nf++)
          #pragma unroll
          for (int rg = 0; rg < 4; rg++) {
            int r = mf * 16 + lk * 4 + rg, c = nf * 16 + lr;
            *reinterpret_cast<unsigned short*>(
                lds + 16384 + w * 2048 + r * 64 + ((c * 2) ^ ((r & 3) << 4))) = f2bf(sc[mf][nf][rg]);
          }
      asm volatile("s_waitcnt lgkmcnt(0)" ::: "memory");  // same-wave ds_write->ds_read
      bf16x8 ap[2];
      #pragma unroll
      for (int mf = 0; mf < 2; mf++) {
        int rp = mf * 16 + lr;
        ap[mf] = *reinterpret_cast<const bf16x8*>(
            lds + 16384 + w * 2048 + rp * 64 + ((lk * 16) ^ ((rp & 3) << 4)));
      }
      #pragma unroll
      for (int vf = 0; vf < 8; vf++) {      // PV
        int rv = vf * 16 + lr;
        bf16x8 bv = *reinterpret_cast<const bf16x8*>(
            lds + 8192 + rv * 64 + ((lk * 16) ^ ((rv & 3) << 4)));
        #pragma unroll
        for (int mf = 0; mf < 2; mf++)
          O[mf][vf] = __builtin_amdgcn_mfma_f32_16x16x32_bf16(ap[mf], bv, O[mf][vf], 0, 0, 0);
      }
    }
    __syncthreads();
  }
  #pragma unroll
  for (int mf = 0; mf < 2; mf++) {          // z[s][h*128+v] bf16
    float inv[4];
    #pragma unroll
    for (int rg = 0; rg < 4; rg++) inv[rg] = 1.0f / l_st[mf][rg];
    #pragma unroll
    for (int vf = 0; vf < 8; vf++)
      #pragma unroll
      for (int rg = 0; rg < 4; rg++) {
        int srow = s0 + w * 32 + mf * 16 + lk * 4 + rg;
        z[(size_t)srow * 2048 + h * 128 + vf * 16 + lr] = f2bf(O[mf][vf][rg] * inv[rg]);
      }
  }
}

// ---------- output GEMM: out(S,D) = z(S,2048) @ obT^T * out_scale ----------
// grid (16,16); 2x2 waves, each 64x64
__global__ __launch_bounds__(256) void k_out(
    const unsigned short* __restrict__ zb, const unsigned short* __restrict__ obT,
    float* __restrict__ out) {
  __shared__ uint4 ldsbuf[2048];
  char* lds = (char*)ldsbuf;
  const int tid = threadIdx.x, l = tid & 63, w = tid >> 6;
  const int lr = l & 15, lk = l >> 4;
  const int s0 = blockIdx.x * 128, n0 = blockIdx.y * 128;
  const int wm = w >> 1, wn = w & 1;
  f32x4 acc[4][4] = {};
  for (int kt = 0; kt < D_MODEL; kt += 64) {
    #pragma unroll
    for (int j = 0; j < 4; j++) {
      int ci = tid + j * 256;
      int r = ci >> 3, c16 = ci & 7;
      int sw = (c16 ^ (r & 7)) * 16;
      bf16x8 av = *reinterpret_cast<const bf16x8*>(zb + (size_t)(s0 + r) * D_MODEL + kt + c16 * 8);
      *reinterpret_cast<bf16x8*>(lds + r * 128 + sw) = av;
      bf16x8 bv = *reinterpret_cast<const bf16x8*>(obT + (size_t)(n0 + r) * D_MODEL + kt + c16 * 8);
      *reinterpret_cast<bf16x8*>(lds + 16384 + r * 128 + sw) = bv;
    }
    __syncthreads();
    #pragma unroll
    for (int kk = 0; kk < 2; kk++) {
      const int kb = kk * 64 + lk * 16;
      bf16x8 a[4], b[4];
      #pragma unroll
      for (int mf = 0; mf < 4; mf++) {
        int rr = wm * 64 + mf * 16 + lr;
        a[mf] = *reinterpret_cast<const bf16x8*>(lds + rr * 128 + (kb ^ ((rr & 7) << 4)));
      }
      #pragma unroll
      for (int nf = 0; nf < 4; nf++) {
        int rn = wn * 64 + nf * 16 + lr;
        b[nf] = *reinterpret_cast<const bf16x8*>(lds + 16384 + rn * 128 + (kb ^ ((rn & 7) << 4)));
      }
      #pragma unroll
      for (int mf = 0; mf < 4; mf++)
        #pragma unroll
        for (int nf = 0; nf < 4; nf++)
          acc[mf][nf] = __builtin_amdgcn_mfma_f32_16x16x32_bf16(a[mf], b[nf], acc[mf][nf], 0, 0, 0);
    }
    __syncthreads();
  }
  const float osc = 0.022097086912079608f;      // 1/sqrt(2048)
  #pragma unroll
  for (int mf = 0; mf < 4; mf++)
    #pragma unroll
    for (int nf = 0; nf < 4; nf++)
      #pragma unroll
      for (int rg = 0; rg < 4; rg++)
        out[(size_t)(s0 + wm * 64 + mf * 16 + lk * 4 + rg) * D_MODEL + n0 + wn * 64 + nf * 16 + lr]
            = acc[mf][nf][rg] * osc;
}

extern "C" void kernel_launch(void* const* d_in, const int* in_sizes, int n_in,
                              void* d_out, int out_size, void* d_ws, size_t ws_size,
                              hipStream_t stream) {
  const float* x = (const float*)d_in[0];
  const float* q = (const float*)d_in[1];
  const float* k = (const float*)d_in[2];
  const float* v = (const float*)d_in[3];
  const float* o = (const float*)d_in[4];
  const float* theta = (const float*)d_in[5];
  float* out = (float*)d_out;

  char* ws = (char*)d_ws;
  const size_t MB = 1u << 20;
  unsigned short* xb  = (unsigned short*)(ws + 0 * MB);
  unsigned short* qbT = (unsigned short*)(ws + 8 * MB);
  unsigned short* kbT = (unsigned short*)(ws + 16 * MB);
  unsigned short* vbT = (unsigned short*)(ws + 24 * MB);
  unsigned short* obT = (unsigned short*)(ws + 32 * MB);
  unsigned short* rq  = (unsigned short*)(ws + 40 * MB);
  unsigned short* rk  = (unsigned short*)(ws + 48 * MB);
  unsigned short* vst = (unsigned short*)(ws + 56 * MB);
  float* sint = (float*)(ws + 64 * MB);
  float* cost = (float*)(ws + 64 * MB + 512 * 1024);
  unsigned short* zb  = (unsigned short*)(ws + 8 * MB);  // reuse qbT after k_proj

  k_cvt<<<dim3(4096), dim3(256), 0, stream>>>(x, xb);
  k_tab<<<dim3(512), dim3(256), 0, stream>>>(theta, sint, cost);
  k_tr<<<dim3(16, 64, 4), dim3(256), 0, stream>>>(q, qbT, 2048, 128);
  k_tr<<<dim3(16, 64, 4), dim3(256), 0, stream>>>(k, kbT, 2048, 128);
  k_tr<<<dim3(16, 64, 4), dim3(256), 0, stream>>>(v, vbT, 2048, 128);
  k_tr<<<dim3(1, 64, 64), dim3(256), 0, stream>>>(o, obT, 2048, 2048);
  k_proj<<<dim3(16, 16, 3), dim3(256), 0, stream>>>(xb, qbT, kbT, vbT, sint, cost, rq, rk, vst);
  k_attn<<<dim3(256), dim3(256), 0, stream>>>(rq, rk, vst, zb);
  k_out<<<dim3(16, 16), dim3(256), 0, stream>>>(zb, obT, out);
}

// Round 2
// 260.123 us; speedup vs baseline: 1.2731x; 1.2731x over previous
//
#include <hip/hip_runtime.h>

// ShrdMHAttention on MI355X (gfx950).
// cvt/transpose -> bf16 MFMA proj GEMM (+RoPE epilogue, attn-scale folded into q)
// -> wave-independent causal flash attention (swapped QK^T, 32x32 MFMA,
//    in-register softmax, kv-split x2) -> combine -> output GEMM.
// Workspace: 0MB xb(S,D)[reused: ml stats] | 8MB qbT[reused: z] | 16MB kbT+vbT
// [reused: O-partials 2x16x2048x128 bf16] | 32MB obT | 40MB rq | 48MB rk |
// 56MB vst | 64MB sin/cos tables

#define S_LEN   2048
#define D_MODEL 2048
#define NHEAD   16
#define DHEAD   128

using f32x4   = __attribute__((ext_vector_type(4))) float;
using f32x16  = __attribute__((ext_vector_type(16))) float;
using bf16x8  = __attribute__((ext_vector_type(8))) __bf16;

__device__ __forceinline__ unsigned short f2bf(float f) {
  unsigned int u = __builtin_bit_cast(unsigned int, f);
  u += 0x7fffu + ((u >> 16) & 1u);          // RNE
  return (unsigned short)(u >> 16);
}
__device__ __forceinline__ float bf2f(unsigned short u) {
  unsigned int v = (unsigned int)u << 16;
  return __builtin_bit_cast(float, v);
}

// ---------- fp32 -> bf16 copy (x) ----------
__global__ void k_cvt(const float* __restrict__ in, unsigned short* __restrict__ out) {
  int i = (blockIdx.x * 256 + threadIdx.x) * 4;
  float4 v = *reinterpret_cast<const float4*>(in + i);
  ushort4 o; o.x = f2bf(v.x); o.y = f2bf(v.y); o.z = f2bf(v.z); o.w = f2bf(v.w);
  *reinterpret_cast<ushort4*>(out + i) = o;
}

// ---------- RoPE sin/cos tables ----------
__global__ void k_tab(const float* __restrict__ theta_p, float* __restrict__ sint,
                      float* __restrict__ cost) {
  int i = blockIdx.x * 256 + threadIdx.x;   // [0, 2048*64)
  int s = i >> 6, c = i & 63;
  float rate = theta_p[0] * (-(float)c / 64.0f);
  float sn, cs;
  sincosf((float)s * rate, &sn, &cs);
  sint[i] = sn; cost[i] = cs;
}

// ---------- transpose+convert: fp32 (B,R,C) -> bf16 (B,C,R) ----------
__global__ void k_tr(const float* __restrict__ in, unsigned short* __restrict__ out,
                     int R, int C) {
  __shared__ float t[32][33];
  int b = blockIdx.x, rt = blockIdx.y, ct = blockIdx.z;
  const float* ip = in + (size_t)b * R * C;
  unsigned short* op = out + (size_t)b * R * C;
  int tx = threadIdx.x & 31, ty = threadIdx.x >> 5;   // 32 x 8
  #pragma unroll
  for (int i = 0; i < 4; i++)
    t[ty + i * 8][tx] = ip[(size_t)(rt * 32 + ty + i * 8) * C + ct * 32 + tx];
  __syncthreads();
  #pragma unroll
  for (int i = 0; i < 4; i++)
    op[(size_t)(ct * 32 + ty + i * 8) * R + rt * 32 + tx] = f2bf(t[tx][ty + i * 8]);
}

// ---------- projection GEMM: C(128 x 128) = x-tile @ W_h^T, epilogue rope/scale ----------
__global__ __launch_bounds__(256) void k_proj(
    const unsigned short* __restrict__ xb,
    const unsigned short* __restrict__ wq, const unsigned short* __restrict__ wk,
    const unsigned short* __restrict__ wv,
    const float* __restrict__ sint, const float* __restrict__ cost,
    unsigned short* __restrict__ rq, unsigned short* __restrict__ rk,
    unsigned short* __restrict__ vst) {
  __shared__ uint4 ldsbuf[2048];            // 32 KB
  char* lds = (char*)ldsbuf;
  const int tid = threadIdx.x, l = tid & 63, w = tid >> 6;
  const int lr = l & 15, lk = l >> 4;
  const int s0 = blockIdx.x * 128;
  const int h = blockIdx.y, which = blockIdx.z;
  const unsigned short* wsel = which == 0 ? wq : (which == 1 ? wk : wv);
  const unsigned short* wbase = wsel + (size_t)h * DHEAD * D_MODEL;

  f32x4 acc[2][8] = {};

  for (int kt = 0; kt < D_MODEL; kt += 64) {
    #pragma unroll
    for (int j = 0; j < 4; j++) {
      int ci = tid + j * 256;
      int r = ci >> 3, c16 = ci & 7;
      int sw = (c16 ^ (r & 7)) * 16;
      bf16x8 av = *reinterpret_cast<const bf16x8*>(xb + (size_t)(s0 + r) * D_MODEL + kt + c16 * 8);
      *reinterpret_cast<bf16x8*>(lds + r * 128 + sw) = av;
      bf16x8 bv = *reinterpret_cast<const bf16x8*>(wbase + (size_t)r * D_MODEL + kt + c16 * 8);
      *reinterpret_cast<bf16x8*>(lds + 16384 + r * 128 + sw) = bv;
    }
    __syncthreads();
    #pragma unroll
    for (int kk = 0; kk < 2; kk++) {
      const int kb = kk * 64 + lk * 16;
      bf16x8 a[2], b[8];
      #pragma unroll
      for (int mf = 0; mf < 2; mf++) {
        int rr = w * 32 + mf * 16 + lr;
        a[mf] = *reinterpret_cast<const bf16x8*>(lds + rr * 128 + (kb ^ ((rr & 7) << 4)));
      }
      #pragma unroll
      for (int nf = 0; nf < 8; nf++) {
        int rn = nf * 16 + lr;
        b[nf] = *reinterpret_cast<const bf16x8*>(lds + 16384 + rn * 128 + (kb ^ ((rn & 7) << 4)));
      }
      #pragma unroll
      for (int mf = 0; mf < 2; mf++)
        #pragma unroll
        for (int nf = 0; nf < 8; nf++)
          acc[mf][nf] = __builtin_amdgcn_mfma_f32_16x16x32_bf16(a[mf], b[nf], acc[mf][nf], 0, 0, 0);
    }
    __syncthreads();
  }

  const float xscale = 0.022097086912079608f;             // 1/sqrt(2048)
  const float qsc = xscale * 0.08838834764831845f;        // * 1/sqrt(128) folded
  if (which < 2) {
    const float sc_out = (which == 0) ? qsc : xscale;
    unsigned short* dst = (which == 0 ? rq : rk) + (size_t)h * S_LEN * DHEAD;
    #pragma unroll
    for (int mf = 0; mf < 2; mf++) {
      #pragma unroll
      for (int nf = 0; nf < 4; nf++) {
        int c1 = nf * 16 + lr;
        #pragma unroll
        for (int rg = 0; rg < 4; rg++) {
          int srow = s0 + w * 32 + mf * 16 + lk * 4 + rg;
          float sn = sint[srow * 64 + c1], cs = cost[srow * 64 + c1];
          float x1 = acc[mf][nf][rg] * sc_out;
          float x2 = acc[mf][nf + 4][rg] * sc_out;
          dst[(size_t)srow * DHEAD + c1]      = f2bf(cs * x1 - sn * x2);
          dst[(size_t)srow * DHEAD + c1 + 64] = f2bf(sn * x1 + cs * x2);
        }
      }
    }
  } else {                                      // v: store transposed vst[h][c][s]
    unsigned short* dst = vst + (size_t)h * DHEAD * S_LEN;
    #pragma unroll
    for (int mf = 0; mf < 2; mf++) {
      int rbase = s0 + w * 32 + mf * 16 + lk * 4;
      #pragma unroll
      for (int nf = 0; nf < 8; nf++) {
        int c = nf * 16 + lr;
        ushort4 ov;
        ov.x = f2bf(acc[mf][nf][0] * xscale); ov.y = f2bf(acc[mf][nf][1] * xscale);
        ov.z = f2bf(acc[mf][nf][2] * xscale); ov.w = f2bf(acc[mf][nf][3] * xscale);
        *reinterpret_cast<ushort4*>(dst + (size_t)c * S_LEN + rbase) = ov;
      }
    }
  }
}

// ---------- causal flash attention: wave-independent, swapped QK^T ----------
// 512 blocks x 256 thr; wave w of block b -> (h, qt, kv-split). Each wave: 32
// q-rows, kv tiles of 32, no LDS, no barriers. P-row lane-local via 32x32 MFMA.
__global__ __launch_bounds__(256, 2) void k_attn2(
    const unsigned short* __restrict__ rq, const unsigned short* __restrict__ rk,
    const unsigned short* __restrict__ vst,
    unsigned short* __restrict__ opart, float2* __restrict__ mlbuf) {
  const int b = blockIdx.x, w = threadIdx.x >> 6, l = threadIdx.x & 63;
  const int hi = l >> 5, qcol = l & 31;
  // wave -> work unit: XCD-local heads, longest qt first
  const int h  = (b & 7) * 2 + ((b >> 3) & 1);
  const int gg = b >> 4;                      // 0..31
  const int qt = 62 - 2 * gg + (w >> 1);
  const int split = w & 1;
  const int s0 = qt * 32;
  const int nt = qt + 1, ntA = (nt + 1) >> 1;
  const int tbeg = split ? ntA : 0, tend = split ? nt : ntA;

  const unsigned short* qrow_p = rq + ((size_t)h * S_LEN + s0 + qcol) * DHEAD + hi * 8;
  bf16x8 qb[8];
  #pragma unroll
  for (int kk = 0; kk < 8; kk++)
    qb[kk] = *reinterpret_cast<const bf16x8*>(qrow_p + kk * 16);

  f32x16 O[4] = {};
  float mrow = -3.0e38f, lrow = 0.0f;
  const unsigned short* krow_base = rk + ((size_t)h * S_LEN + qcol) * DHEAD + hi * 8;
  const unsigned short* vbase = vst + ((size_t)h * DHEAD + qcol) * S_LEN + hi * 8;

  for (int t = tbeg; t < tend; t++) {
    const int t0 = t * 32;
    // --- QK^T: sc[kv(reg), q(lane)] ---
    const unsigned short* kp = krow_base + (size_t)t0 * DHEAD;
    bf16x8 ka[8];
    #pragma unroll
    for (int kk = 0; kk < 8; kk++)
      ka[kk] = *reinterpret_cast<const bf16x8*>(kp + kk * 16);
    f32x16 sc = {};
    #pragma unroll
    for (int kk = 0; kk < 8; kk++)
      sc = __builtin_amdgcn_mfma_f32_32x32x16_bf16(ka[kk], qb[kk], sc, 0, 0, 0);

    float p[16];
    #pragma unroll
    for (int r = 0; r < 16; r++) p[r] = sc[r];
    if (t == qt) {                            // diagonal tile: causal mask
      #pragma unroll
      for (int r = 0; r < 16; r++)
        if (((r & 3) + 8 * (r >> 2) + 4 * hi) > qcol) p[r] = -1.0e9f;
    }
    // --- row max (pairwise tree + one cross-half swap) ---
    float mx[8];
    #pragma unroll
    for (int i = 0; i < 8; i++) mx[i] = fmaxf(p[2 * i], p[2 * i + 1]);
    #pragma unroll
    for (int i = 0; i < 4; i++) mx[i] = fmaxf(mx[i], mx[i + 4]);
    mx[0] = fmaxf(mx[0], mx[2]); mx[1] = fmaxf(mx[1], mx[3]);
    float pmax = fmaxf(mx[0], mx[1]);
    pmax = fmaxf(pmax, __shfl_xor(pmax, 32, 64));
    // --- defer-max rescale ---
    if (__any(pmax > mrow + 8.0f)) {
      float mn = fmaxf(mrow, pmax);
      float sf = __expf(mrow - mn);
      lrow *= sf; mrow = mn;
      #pragma unroll
      for (int vc = 0; vc < 4; vc++)
        #pragma unroll
        for (int r = 0; r < 16; r++) O[vc][r] *= sf;
    }
    #pragma unroll
    for (int r = 0; r < 16; r++) p[r] = __expf(p[r] - mrow);
    float sm[8];
    #pragma unroll
    for (int i = 0; i < 8; i++) sm[i] = p[2 * i] + p[2 * i + 1];
    #pragma unroll
    for (int i = 0; i < 4; i++) sm[i] += sm[i + 4];
    float psum = (sm[0] + sm[1]) + (sm[2] + sm[3]);
    psum += __shfl_xor(psum, 32, 64);
    lrow += psum;
    // --- pack P -> bf16 B-frags (kv-chunks c=0,1 of 16) ---
    unsigned int pk[2][4], sw[2][4];
    #pragma unroll
    for (int c = 0; c < 2; c++)
      #pragma unroll
      for (int k = 0; k < 4; k++) {
        unsigned int r_;
        asm("v_cvt_pk_bf16_f32 %0, %1, %2" : "=v"(r_)
            : "v"(p[8 * c + 2 * k]), "v"(p[8 * c + 2 * k + 1]));
        pk[c][k] = r_;
        sw[c][k] = (unsigned int)__shfl_xor((int)r_, 32, 64);
      }
    bf16x8 pb[2];
    #pragma unroll
    for (int c = 0; c < 2; c++) {
      union { unsigned int u[4]; bf16x8 v; } bw;
      bw.u[0] = hi ? sw[c][2] : pk[c][0];
      bw.u[1] = hi ? sw[c][3] : pk[c][1];
      bw.u[2] = hi ? pk[c][2] : sw[c][0];
      bw.u[3] = hi ? pk[c][3] : sw[c][1];
      pb[c] = bw.v;
    }
    // --- PV: O[v(reg), q(lane)] += V^T-chunk x P ---
    const unsigned short* vp = vbase + t0;
    #pragma unroll
    for (int vc = 0; vc < 4; vc++) {
      bf16x8 va0 = *reinterpret_cast<const bf16x8*>(vp + (size_t)(vc * 32) * S_LEN);
      bf16x8 va1 = *reinterpret_cast<const bf16x8*>(vp + (size_t)(vc * 32) * S_LEN + 16);
      O[vc] = __builtin_amdgcn_mfma_f32_32x32x16_bf16(va0, pb[0], O[vc], 0, 0, 0);
      O[vc] = __builtin_amdgcn_mfma_f32_32x32x16_bf16(va1, pb[1], O[vc], 0, 0, 0);
    }
  }
  // --- write partial: opart[split][h][s][v] bf16 normalized, ml stats ---
  float inv = lrow > 0.0f ? 1.0f / lrow : 0.0f;
  unsigned short* op = opart + ((size_t)(split * NHEAD + h) * S_LEN + s0 + qcol) * DHEAD;
  #pragma unroll
  for (int vc = 0; vc < 4; vc++)
    #pragma unroll
    for (int g = 0; g < 4; g++) {
      int v0 = vc * 32 + 8 * g + 4 * hi;
      ushort4 ov;
      ov.x = f2bf(O[vc][4 * g + 0] * inv); ov.y = f2bf(O[vc][4 * g + 1] * inv);
      ov.z = f2bf(O[vc][4 * g + 2] * inv); ov.w = f2bf(O[vc][4 * g + 3] * inv);
      *reinterpret_cast<ushort4*>(op + v0) = ov;
    }
  if (l < 32)
    mlbuf[(size_t)(split * NHEAD + h) * S_LEN + s0 + qcol] = make_float2(mrow, lrow);
}

// ---------- combine the two kv-splits ----------
__global__ void k_comb(const unsigned short* __restrict__ opart,
                       const float2* __restrict__ mlbuf,
                       unsigned short* __restrict__ z) {
  int g = blockIdx.x * 256 + threadIdx.x;     // 16h * 2048q * 16vg
  int vg = g & 15, q = (g >> 4) & 2047, h = g >> 15;
  float2 a = mlbuf[(size_t)h * S_LEN + q];
  float2 b = mlbuf[(size_t)(NHEAD + h) * S_LEN + q];
  float m = fmaxf(a.x, b.x);
  float w1 = a.y > 0.0f ? a.y * __expf(a.x - m) : 0.0f;
  float w2 = b.y > 0.0f ? b.y * __expf(b.x - m) : 0.0f;
  float wi = 1.0f / (w1 + w2);
  w1 *= wi; w2 *= wi;
  const unsigned short* o1 = opart + ((size_t)h * S_LEN + q) * DHEAD + vg * 8;
  const unsigned short* o2 = o1 + (size_t)NHEAD * S_LEN * DHEAD;
  bf16x8 v1 = *reinterpret_cast<const bf16x8*>(o1);
  bf16x8 v2 = *reinterpret_cast<const bf16x8*>(o2);
  unsigned short* zp = z + (size_t)q * D_MODEL + h * DHEAD + vg * 8;
  ushort4 lo, hi4;
  unsigned short tmp[8];
  #pragma unroll
  for (int j = 0; j < 8; j++) {
    float f1 = (float)v1[j], f2 = (float)v2[j];
    tmp[j] = f2bf(w1 * f1 + w2 * f2);
  }
  lo.x = tmp[0]; lo.y = tmp[1]; lo.z = tmp[2]; lo.w = tmp[3];
  hi4.x = tmp[4]; hi4.y = tmp[5]; hi4.z = tmp[6]; hi4.w = tmp[7];
  *reinterpret_cast<ushort4*>(zp) = lo;
  *reinterpret_cast<ushort4*>(zp + 4) = hi4;
}

// ---------- output GEMM: out(S,D) = z(S,2048) @ obT^T * out_scale ----------
__global__ __launch_bounds__(256) void k_out(
    const unsigned short* __restrict__ zb, const unsigned short* __restrict__ obT,
    float* __restrict__ out) {
  __shared__ uint4 ldsbuf[2048];
  char* lds = (char*)ldsbuf;
  const int tid = threadIdx.x, l = tid & 63, w = tid >> 6;
  const int lr = l & 15, lk = l >> 4;
  const int s0 = blockIdx.x * 128, n0 = blockIdx.y * 128;
  const int wm = w >> 1, wn = w & 1;
  f32x4 acc[4][4] = {};
  for (int kt = 0; kt < D_MODEL; kt += 64) {
    #pragma unroll
    for (int j = 0; j < 4; j++) {
      int ci = tid + j * 256;
      int r = ci >> 3, c16 = ci & 7;
      int sw = (c16 ^ (r & 7)) * 16;
      bf16x8 av = *reinterpret_cast<const bf16x8*>(zb + (size_t)(s0 + r) * D_MODEL + kt + c16 * 8);
      *reinterpret_cast<bf16x8*>(lds + r * 128 + sw) = av;
      bf16x8 bv = *reinterpret_cast<const bf16x8*>(obT + (size_t)(n0 + r) * D_MODEL + kt + c16 * 8);
      *reinterpret_cast<bf16x8*>(lds + 16384 + r * 128 + sw) = bv;
    }
    __syncthreads();
    #pragma unroll
    for (int kk = 0; kk < 2; kk++) {
      const int kb = kk * 64 + lk * 16;
      bf16x8 a[4], b[4];
      #pragma unroll
      for (int mf = 0; mf < 4; mf++) {
        int rr = wm * 64 + mf * 16 + lr;
        a[mf] = *reinterpret_cast<const bf16x8*>(lds + rr * 128 + (kb ^ ((rr & 7) << 4)));
      }
      #pragma unroll
      for (int nf = 0; nf < 4; nf++) {
        int rn = wn * 64 + nf * 16 + lr;
        b[nf] = *reinterpret_cast<const bf16x8*>(lds + 16384 + rn * 128 + (kb ^ ((rn & 7) << 4)));
      }
      #pragma unroll
      for (int mf = 0; mf < 4; mf++)
        #pragma unroll
        for (int nf = 0; nf < 4; nf++)
          acc[mf][nf] = __builtin_amdgcn_mfma_f32_16x16x32_bf16(a[mf], b[nf], acc[mf][nf], 0, 0, 0);
    }
    __syncthreads();
  }
  const float osc = 0.022097086912079608f;      // 1/sqrt(2048)
  #pragma unroll
  for (int mf = 0; mf < 4; mf++)
    #pragma unroll
    for (int nf = 0; nf < 4; nf++)
      #pragma unroll
      for (int rg = 0; rg < 4; rg++)
        out[(size_t)(s0 + wm * 64 + mf * 16 + lk * 4 + rg) * D_MODEL + n0 + wn * 64 + nf * 16 + lr]
            = acc[mf][nf][rg] * osc;
}

extern "C" void kernel_launch(void* const* d_in, const int* in_sizes, int n_in,
                              void* d_out, int out_size, void* d_ws, size_t ws_size,
                              hipStream_t stream) {
  const float* x = (const float*)d_in[0];
  const float* q = (const float*)d_in[1];
  const float* k = (const float*)d_in[2];
  const float* v = (const float*)d_in[3];
  const float* o = (const float*)d_in[4];
  const float* theta = (const float*)d_in[5];
  float* out = (float*)d_out;

  char* ws = (char*)d_ws;
  const size_t MB = 1u << 20;
  unsigned short* xb  = (unsigned short*)(ws + 0 * MB);
  unsigned short* qbT = (unsigned short*)(ws + 8 * MB);
  unsigned short* kbT = (unsigned short*)(ws + 16 * MB);
  unsigned short* vbT = (unsigned short*)(ws + 24 * MB);
  unsigned short* obT = (unsigned short*)(ws + 32 * MB);
  unsigned short* rq  = (unsigned short*)(ws + 40 * MB);
  unsigned short* rk  = (unsigned short*)(ws + 48 * MB);
  unsigned short* vst = (unsigned short*)(ws + 56 * MB);
  float* sint = (float*)(ws + 64 * MB);
  float* cost = (float*)(ws + 64 * MB + 512 * 1024);
  unsigned short* zb    = (unsigned short*)(ws + 8 * MB);   // reuse qbT
  unsigned short* opart = (unsigned short*)(ws + 16 * MB);  // reuse kbT+vbT (16MB)
  float2* mlbuf         = (float2*)(ws + 0 * MB);           // reuse xb (512KB)

  k_cvt<<<dim3(4096), dim3(256), 0, stream>>>(x, xb);
  k_tab<<<dim3(512), dim3(256), 0, stream>>>(theta, sint, cost);
  k_tr<<<dim3(16, 64, 4), dim3(256), 0, stream>>>(q, qbT, 2048, 128);
  k_tr<<<dim3(16, 64, 4), dim3(256), 0, stream>>>(k, kbT, 2048, 128);
  k_tr<<<dim3(16, 64, 4), dim3(256), 0, stream>>>(v, vbT, 2048, 128);
  k_tr<<<dim3(1, 64, 64), dim3(256), 0, stream>>>(o, obT, 2048, 2048);
  k_proj<<<dim3(16, 16, 3), dim3(256), 0, stream>>>(xb, qbT, kbT, vbT, sint, cost, rq, rk, vst);
  k_attn2<<<dim3(512), dim3(256), 0, stream>>>(rq, rk, vst, opart, mlbuf);
  k_comb<<<dim3(2048), dim3(256), 0, stream>>>(opart, mlbuf, zb);
  k_out<<<dim3(16, 16), dim3(256), 0, stream>>>(zb, obT, out);
}

// Round 4
// 246.238 us; speedup vs baseline: 1.3449x; 1.0564x over previous
//
#include <hip/hip_runtime.h>

// ShrdMHAttention on MI355X (gfx950).
// cvt/transpose -> bf16 MFMA proj GEMM (+RoPE epilogue, attn-scale folded into q)
// -> causal flash attention (padded-LDS staged K/V, swapped QK^T, in-register
//    softmax — R2-verified per-wave math, KVBLK=32) -> combine -> output GEMM.
// Workspace: 0MB xb[reused: ml stats] | 8MB qbT[reused: z] | 16MB kbT+vbT
// [reused: O-partials 2x16x2048x128 bf16] | 32MB obT | 40MB rq | 48MB rk |
// 56MB vst | 64MB sin/cos tables

#define S_LEN   2048
#define D_MODEL 2048
#define NHEAD   16
#define DHEAD   128

using f32x4   = __attribute__((ext_vector_type(4))) float;
using f32x16  = __attribute__((ext_vector_type(16))) float;
using bf16x8  = __attribute__((ext_vector_type(8))) __bf16;

__device__ __forceinline__ unsigned short f2bf(float f) {
  unsigned int u = __builtin_bit_cast(unsigned int, f);
  u += 0x7fffu + ((u >> 16) & 1u);          // RNE
  return (unsigned short)(u >> 16);
}

// ---------- fp32 -> bf16 copy (x) ----------
__global__ void k_cvt(const float* __restrict__ in, unsigned short* __restrict__ out) {
  int i = (blockIdx.x * 256 + threadIdx.x) * 4;
  float4 v = *reinterpret_cast<const float4*>(in + i);
  ushort4 o; o.x = f2bf(v.x); o.y = f2bf(v.y); o.z = f2bf(v.z); o.w = f2bf(v.w);
  *reinterpret_cast<ushort4*>(out + i) = o;
}

// ---------- RoPE sin/cos tables ----------
__global__ void k_tab(const float* __restrict__ theta_p, float* __restrict__ sint,
                      float* __restrict__ cost) {
  int i = blockIdx.x * 256 + threadIdx.x;   // [0, 2048*64)
  int s = i >> 6, c = i & 63;
  float rate = theta_p[0] * (-(float)c / 64.0f);
  float sn, cs;
  sincosf((float)s * rate, &sn, &cs);
  sint[i] = sn; cost[i] = cs;
}

// ---------- transpose+convert: fp32 (B,R,C) -> bf16 (B,C,R) ----------
__global__ void k_tr(const float* __restrict__ in, unsigned short* __restrict__ out,
                     int R, int C) {
  __shared__ float t[32][33];
  int b = blockIdx.x, rt = blockIdx.y, ct = blockIdx.z;
  const float* ip = in + (size_t)b * R * C;
  unsigned short* op = out + (size_t)b * R * C;
  int tx = threadIdx.x & 31, ty = threadIdx.x >> 5;   // 32 x 8
  #pragma unroll
  for (int i = 0; i < 4; i++)
    t[ty + i * 8][tx] = ip[(size_t)(rt * 32 + ty + i * 8) * C + ct * 32 + tx];
  __syncthreads();
  #pragma unroll
  for (int i = 0; i < 4; i++)
    op[(size_t)(ct * 32 + ty + i * 8) * R + rt * 32 + tx] = f2bf(t[tx][ty + i * 8]);
}

// ---------- projection GEMM: C(128 x 128) = x-tile @ W_h^T, epilogue rope/scale ----------
__global__ __launch_bounds__(256) void k_proj(
    const unsigned short* __restrict__ xb,
    const unsigned short* __restrict__ wq, const unsigned short* __restrict__ wk,
    const unsigned short* __restrict__ wv,
    const float* __restrict__ sint, const float* __restrict__ cost,
    unsigned short* __restrict__ rq, unsigned short* __restrict__ rk,
    unsigned short* __restrict__ vst) {
  __shared__ uint4 ldsbuf[2048];            // 32 KB
  char* lds = (char*)ldsbuf;
  const int tid = threadIdx.x, l = tid & 63, w = tid >> 6;
  const int lr = l & 15, lk = l >> 4;
  const int s0 = blockIdx.x * 128;
  const int h = blockIdx.y, which = blockIdx.z;
  const unsigned short* wsel = which == 0 ? wq : (which == 1 ? wk : wv);
  const unsigned short* wbase = wsel + (size_t)h * DHEAD * D_MODEL;

  f32x4 acc[2][8] = {};

  for (int kt = 0; kt < D_MODEL; kt += 64) {
    #pragma unroll
    for (int j = 0; j < 4; j++) {
      int ci = tid + j * 256;
      int r = ci >> 3, c16 = ci & 7;
      int sw = (c16 ^ (r & 7)) * 16;
      bf16x8 av = *reinterpret_cast<const bf16x8*>(xb + (size_t)(s0 + r) * D_MODEL + kt + c16 * 8);
      *reinterpret_cast<bf16x8*>(lds + r * 128 + sw) = av;
      bf16x8 bv = *reinterpret_cast<const bf16x8*>(wbase + (size_t)r * D_MODEL + kt + c16 * 8);
      *reinterpret_cast<bf16x8*>(lds + 16384 + r * 128 + sw) = bv;
    }
    __syncthreads();
    #pragma unroll
    for (int kk = 0; kk < 2; kk++) {
      const int kb = kk * 64 + lk * 16;
      bf16x8 a[2], b[8];
      #pragma unroll
      for (int mf = 0; mf < 2; mf++) {
        int rr = w * 32 + mf * 16 + lr;
        a[mf] = *reinterpret_cast<const bf16x8*>(lds + rr * 128 + (kb ^ ((rr & 7) << 4)));
      }
      #pragma unroll
      for (int nf = 0; nf < 8; nf++) {
        int rn = nf * 16 + lr;
        b[nf] = *reinterpret_cast<const bf16x8*>(lds + 16384 + rn * 128 + (kb ^ ((rn & 7) << 4)));
      }
      #pragma unroll
      for (int mf = 0; mf < 2; mf++)
        #pragma unroll
        for (int nf = 0; nf < 8; nf++)
          acc[mf][nf] = __builtin_amdgcn_mfma_f32_16x16x32_bf16(a[mf], b[nf], acc[mf][nf], 0, 0, 0);
    }
    __syncthreads();
  }

  const float xscale = 0.022097086912079608f;             // 1/sqrt(2048)
  const float qsc = xscale * 0.08838834764831845f;        // * 1/sqrt(128) folded
  if (which < 2) {
    const float sc_out = (which == 0) ? qsc : xscale;
    unsigned short* dst = (which == 0 ? rq : rk) + (size_t)h * S_LEN * DHEAD;
    #pragma unroll
    for (int mf = 0; mf < 2; mf++) {
      #pragma unroll
      for (int nf = 0; nf < 4; nf++) {
        int c1 = nf * 16 + lr;
        #pragma unroll
        for (int rg = 0; rg < 4; rg++) {
          int srow = s0 + w * 32 + mf * 16 + lk * 4 + rg;
          float sn = sint[srow * 64 + c1], cs = cost[srow * 64 + c1];
          float x1 = acc[mf][nf][rg] * sc_out;
          float x2 = acc[mf][nf + 4][rg] * sc_out;
          dst[(size_t)srow * DHEAD + c1]      = f2bf(cs * x1 - sn * x2);
          dst[(size_t)srow * DHEAD + c1 + 64] = f2bf(sn * x1 + cs * x2);
        }
      }
    }
  } else {                                      // v: store transposed vst[h][c][s]
    unsigned short* dst = vst + (size_t)h * DHEAD * S_LEN;
    #pragma unroll
    for (int mf = 0; mf < 2; mf++) {
      int rbase = s0 + w * 32 + mf * 16 + lk * 4;
      #pragma unroll
      for (int nf = 0; nf < 8; nf++) {
        int c = nf * 16 + lr;
        ushort4 ov;
        ov.x = f2bf(acc[mf][nf][0] * xscale); ov.y = f2bf(acc[mf][nf][1] * xscale);
        ov.z = f2bf(acc[mf][nf][2] * xscale); ov.w = f2bf(acc[mf][nf][3] * xscale);
        *reinterpret_cast<ushort4*>(dst + (size_t)c * S_LEN + rbase) = ov;
      }
    }
  }
}

// ---------- causal flash attention v4: R2 math + padded-LDS staged K/V ----------
// 512 blocks = (2 kvsplit x 16 qt x 16 h); 4 waves x 32 q-rows; KVBLK=32.
// K[32] rows @272B, Vt[128] rows @80B (padded: uniform bank use). 2 barriers
// per tile; next tile's global loads issued under compute (T14).
__global__ __launch_bounds__(256, 2) void k_attn4(
    const unsigned short* __restrict__ rq, const unsigned short* __restrict__ rk,
    const unsigned short* __restrict__ vst,
    unsigned short* __restrict__ opart, float2* __restrict__ mlbuf) {
  __shared__ uint4 ldsbuf[1184];            // 18944B: K @0 (8704), Vt @8704 (10240)
  char* lds = (char*)ldsbuf;
  const int tid = threadIdx.x, l = tid & 63, w = tid >> 6;
  const int hi = l >> 5, qcol = l & 31;
  const int b = blockIdx.x;
  const int split = b >> 8, bb = b & 255;
  const int h = bb & 15;                    // blocks of head h all land on XCD h&7
  const int qt = split ? (bb >> 4) : 15 - (bb >> 4);   // long+short pairing
  const int ntile = 2 * qt + 2;
  const int tbeg = split ? ntile : 0;
  const int tend = split ? 2 * ntile : ntile;
  const int s0w = qt * 128 + w * 32;
  const int wlast = s0w + 31;
  const int dtile = s0w >> 5;               // diagonal tile index

  const unsigned short* rk_h  = rk  + (size_t)h * S_LEN * DHEAD;
  const unsigned short* vst_h = vst + (size_t)h * DHEAD * S_LEN;

  // Q fragments (B-operand of swapped QK^T), scales pre-folded in k_proj
  const unsigned short* qrow_p = rq + ((size_t)h * S_LEN + s0w + qcol) * DHEAD + hi * 8;
  bf16x8 qb[8];
  #pragma unroll
  for (int kk = 0; kk < 8; kk++)
    qb[kk] = *reinterpret_cast<const bf16x8*>(qrow_p + kk * 16);

  f32x16 O[4] = {};
  float mrow = -3.0e38f, lrow = 0.0f;

  uint4 kreg[2], vreg[2];
  {                                         // prefetch tile tbeg
    const int t0 = tbeg * 32;
    #pragma unroll
    for (int j = 0; j < 2; j++) {
      int ci = tid + j * 256;
      kreg[j] = *reinterpret_cast<const uint4*>(rk_h + (size_t)(t0 + (ci >> 4)) * DHEAD + (ci & 15) * 8);
      vreg[j] = *reinterpret_cast<const uint4*>(vst_h + (size_t)(ci >> 2) * S_LEN + t0 + (ci & 3) * 8);
    }
  }

  for (int t = tbeg; t < tend; t++) {
    __syncthreads();                        // prior tile's LDS reads done
    #pragma unroll
    for (int j = 0; j < 2; j++) {
      int ci = tid + j * 256;
      *reinterpret_cast<uint4*>(lds + (ci >> 4) * 272 + (ci & 15) * 16) = kreg[j];
      *reinterpret_cast<uint4*>(lds + 8704 + (ci >> 2) * 80 + (ci & 3) * 16) = vreg[j];
    }
    if (t + 1 < tend) {                     // T14: issue next tile's loads now
      const int t0n = (t + 1) * 32;
      #pragma unroll
      for (int j = 0; j < 2; j++) {
        int ci = tid + j * 256;
        kreg[j] = *reinterpret_cast<const uint4*>(rk_h + (size_t)(t0n + (ci >> 4)) * DHEAD + (ci & 15) * 8);
        vreg[j] = *reinterpret_cast<const uint4*>(vst_h + (size_t)(ci >> 2) * S_LEN + t0n + (ci & 3) * 8);
      }
    }
    __syncthreads();                        // staged tile visible
    const int tt0 = t * 32;
    if (tt0 <= wlast) {
      // --- QK^T: sc[kv(reg), q(lane)] --- (R2-verified math from here on)
      f32x16 sc = {};
      #pragma unroll
      for (int kk = 0; kk < 8; kk++) {
        bf16x8 ka = *reinterpret_cast<const bf16x8*>(lds + qcol * 272 + kk * 32 + hi * 16);
        sc = __builtin_amdgcn_mfma_f32_32x32x16_bf16(ka, qb[kk], sc, 0, 0, 0);
      }
      float p[16];
      #pragma unroll
      for (int r = 0; r < 16; r++) p[r] = sc[r];
      if (t == dtile) {                     // diagonal tile: causal mask
        #pragma unroll
        for (int r = 0; r < 16; r++)
          if (((r & 3) + 8 * (r >> 2) + 4 * hi) > qcol) p[r] = -1.0e9f;
      }
      // --- row max (pairwise tree + one cross-half swap) ---
      float mx[8];
      #pragma unroll
      for (int i = 0; i < 8; i++) mx[i] = fmaxf(p[2 * i], p[2 * i + 1]);
      #pragma unroll
      for (int i = 0; i < 4; i++) mx[i] = fmaxf(mx[i], mx[i + 4]);
      mx[0] = fmaxf(mx[0], mx[2]); mx[1] = fmaxf(mx[1], mx[3]);
      float pmax = fmaxf(mx[0], mx[1]);
      pmax = fmaxf(pmax, __shfl_xor(pmax, 32, 64));
      // --- defer-max rescale ---
      if (__any(pmax > mrow + 8.0f)) {
        float mn = fmaxf(mrow, pmax);
        float sf = __expf(mrow - mn);
        lrow *= sf; mrow = mn;
        #pragma unroll
        for (int vc = 0; vc < 4; vc++)
          #pragma unroll
          for (int r = 0; r < 16; r++) O[vc][r] *= sf;
      }
      #pragma unroll
      for (int r = 0; r < 16; r++) p[r] = __expf(p[r] - mrow);
      float sm[8];
      #pragma unroll
      for (int i = 0; i < 8; i++) sm[i] = p[2 * i] + p[2 * i + 1];
      #pragma unroll
      for (int i = 0; i < 4; i++) sm[i] += sm[i + 4];
      float psum = (sm[0] + sm[1]) + (sm[2] + sm[3]);
      psum += __shfl_xor(psum, 32, 64);
      lrow += psum;
      // --- pack P -> bf16 B-frags (kv-chunks c=0,1 of 16) ---
      unsigned int pk[2][4], sw[2][4];
      #pragma unroll
      for (int c = 0; c < 2; c++)
        #pragma unroll
        for (int k = 0; k < 4; k++) {
          unsigned int r_;
          asm("v_cvt_pk_bf16_f32 %0, %1, %2" : "=v"(r_)
              : "v"(p[8 * c + 2 * k]), "v"(p[8 * c + 2 * k + 1]));
          pk[c][k] = r_;
          sw[c][k] = (unsigned int)__shfl_xor((int)r_, 32, 64);
        }
      bf16x8 pb[2];
      #pragma unroll
      for (int c = 0; c < 2; c++) {
        union { unsigned int u[4]; bf16x8 v; } bw;
        bw.u[0] = hi ? sw[c][2] : pk[c][0];
        bw.u[1] = hi ? sw[c][3] : pk[c][1];
        bw.u[2] = hi ? pk[c][2] : sw[c][0];
        bw.u[3] = hi ? pk[c][3] : sw[c][1];
        pb[c] = bw.v;
      }
      // --- PV from LDS V^T ---
      #pragma unroll
      for (int vc = 0; vc < 4; vc++) {
        const char* vrow = lds + 8704 + (vc * 32 + qcol) * 80 + hi * 16;
        bf16x8 va0 = *reinterpret_cast<const bf16x8*>(vrow);
        bf16x8 va1 = *reinterpret_cast<const bf16x8*>(vrow + 32);
        O[vc] = __builtin_amdgcn_mfma_f32_32x32x16_bf16(va0, pb[0], O[vc], 0, 0, 0);
        O[vc] = __builtin_amdgcn_mfma_f32_32x32x16_bf16(va1, pb[1], O[vc], 0, 0, 0);
      }
    }
  }
  // --- write partial: opart[split][h][s][v] bf16 normalized, ml stats ---
  float inv = lrow > 0.0f ? 1.0f / lrow : 0.0f;
  unsigned short* op = opart + ((size_t)(split * NHEAD + h) * S_LEN + s0w + qcol) * DHEAD;
  #pragma unroll
  for (int vc = 0; vc < 4; vc++)
    #pragma unroll
    for (int g = 0; g < 4; g++) {
      int v0 = vc * 32 + 8 * g + 4 * hi;
      ushort4 ov;
      ov.x = f2bf(O[vc][4 * g + 0] * inv); ov.y = f2bf(O[vc][4 * g + 1] * inv);
      ov.z = f2bf(O[vc][4 * g + 2] * inv); ov.w = f2bf(O[vc][4 * g + 3] * inv);
      *reinterpret_cast<ushort4*>(op + v0) = ov;
    }
  if (l < 32)
    mlbuf[(size_t)(split * NHEAD + h) * S_LEN + s0w + qcol] = make_float2(mrow, lrow);
}

// ---------- combine the two kv-splits ----------
__global__ void k_comb(const unsigned short* __restrict__ opart,
                       const float2* __restrict__ mlbuf,
                       unsigned short* __restrict__ z) {
  int g = blockIdx.x * 256 + threadIdx.x;     // 16h * 2048q * 16vg
  int vg = g & 15, q = (g >> 4) & 2047, h = g >> 15;
  float2 a = mlbuf[(size_t)h * S_LEN + q];
  float2 b = mlbuf[(size_t)(NHEAD + h) * S_LEN + q];
  float m = fmaxf(a.x, b.x);
  float w1 = a.y > 0.0f ? a.y * __expf(a.x - m) : 0.0f;
  float w2 = b.y > 0.0f ? b.y * __expf(b.x - m) : 0.0f;
  float wi = 1.0f / (w1 + w2);
  w1 *= wi; w2 *= wi;
  const unsigned short* o1 = opart + ((size_t)h * S_LEN + q) * DHEAD + vg * 8;
  const unsigned short* o2 = o1 + (size_t)NHEAD * S_LEN * DHEAD;
  bf16x8 v1 = *reinterpret_cast<const bf16x8*>(o1);
  bf16x8 v2 = *reinterpret_cast<const bf16x8*>(o2);
  unsigned short* zp = z + (size_t)q * D_MODEL + h * DHEAD + vg * 8;
  ushort4 lo, hi4;
  unsigned short tmp[8];
  #pragma unroll
  for (int j = 0; j < 8; j++) {
    float f1 = (float)v1[j], f2 = (float)v2[j];
    tmp[j] = f2bf(w1 * f1 + w2 * f2);
  }
  lo.x = tmp[0]; lo.y = tmp[1]; lo.z = tmp[2]; lo.w = tmp[3];
  hi4.x = tmp[4]; hi4.y = tmp[5]; hi4.z = tmp[6]; hi4.w = tmp[7];
  *reinterpret_cast<ushort4*>(zp) = lo;
  *reinterpret_cast<ushort4*>(zp + 4) = hi4;
}

// ---------- output GEMM: out(S,D) = z(S,2048) @ obT^T * out_scale ----------
__global__ __launch_bounds__(256) void k_out(
    const unsigned short* __restrict__ zb, const unsigned short* __restrict__ obT,
    float* __restrict__ out) {
  __shared__ uint4 ldsbuf[2048];
  char* lds = (char*)ldsbuf;
  const int tid = threadIdx.x, l = tid & 63, w = tid >> 6;
  const int lr = l & 15, lk = l >> 4;
  const int s0 = blockIdx.x * 128, n0 = blockIdx.y * 128;
  const int wm = w >> 1, wn = w & 1;
  f32x4 acc[4][4] = {};
  for (int kt = 0; kt < D_MODEL; kt += 64) {
    #pragma unroll
    for (int j = 0; j < 4; j++) {
      int ci = tid + j * 256;
      int r = ci >> 3, c16 = ci & 7;
      int sw = (c16 ^ (r & 7)) * 16;
      bf16x8 av = *reinterpret_cast<const bf16x8*>(zb + (size_t)(s0 + r) * D_MODEL + kt + c16 * 8);
      *reinterpret_cast<bf16x8*>(lds + r * 128 + sw) = av;
      bf16x8 bv = *reinterpret_cast<const bf16x8*>(obT + (size_t)(n0 + r) * D_MODEL + kt + c16 * 8);
      *reinterpret_cast<bf16x8*>(lds + 16384 + r * 128 + sw) = bv;
    }
    __syncthreads();
    #pragma unroll
    for (int kk = 0; kk < 2; kk++) {
      const int kb = kk * 64 + lk * 16;
      bf16x8 a[4], b[4];
      #pragma unroll
      for (int mf = 0; mf < 4; mf++) {
        int rr = wm * 64 + mf * 16 + lr;
        a[mf] = *reinterpret_cast<const bf16x8*>(lds + rr * 128 + (kb ^ ((rr & 7) << 4)));
      }
      #pragma unroll
      for (int nf = 0; nf < 4; nf++) {
        int rn = wn * 64 + nf * 16 + lr;
        b[nf] = *reinterpret_cast<const bf16x8*>(lds + 16384 + rn * 128 + (kb ^ ((rn & 7) << 4)));
      }
      #pragma unroll
      for (int mf = 0; mf < 4; mf++)
        #pragma unroll
        for (int nf = 0; nf < 4; nf++)
          acc[mf][nf] = __builtin_amdgcn_mfma_f32_16x16x32_bf16(a[mf], b[nf], acc[mf][nf], 0, 0, 0);
    }
    __syncthreads();
  }
  const float osc = 0.022097086912079608f;      // 1/sqrt(2048)
  #pragma unroll
  for (int mf = 0; mf < 4; mf++)
    #pragma unroll
    for (int nf = 0; nf < 4; nf++)
      #pragma unroll
      for (int rg = 0; rg < 4; rg++)
        out[(size_t)(s0 + wm * 64 + mf * 16 + lk * 4 + rg) * D_MODEL + n0 + wn * 64 + nf * 16 + lr]
            = acc[mf][nf][rg] * osc;
}

extern "C" void kernel_launch(void* const* d_in, const int* in_sizes, int n_in,
                              void* d_out, int out_size, void* d_ws, size_t ws_size,
                              hipStream_t stream) {
  const float* x = (const float*)d_in[0];
  const float* q = (const float*)d_in[1];
  const float* k = (const float*)d_in[2];
  const float* v = (const float*)d_in[3];
  const float* o = (const float*)d_in[4];
  const float* theta = (const float*)d_in[5];
  float* out = (float*)d_out;

  char* ws = (char*)d_ws;
  const size_t MB = 1u << 20;
  unsigned short* xb  = (unsigned short*)(ws + 0 * MB);
  unsigned short* qbT = (unsigned short*)(ws + 8 * MB);
  unsigned short* kbT = (unsigned short*)(ws + 16 * MB);
  unsigned short* vbT = (unsigned short*)(ws + 24 * MB);
  unsigned short* obT = (unsigned short*)(ws + 32 * MB);
  unsigned short* rq  = (unsigned short*)(ws + 40 * MB);
  unsigned short* rk  = (unsigned short*)(ws + 48 * MB);
  unsigned short* vst = (unsigned short*)(ws + 56 * MB);
  float* sint = (float*)(ws + 64 * MB);
  float* cost = (float*)(ws + 64 * MB + 512 * 1024);
  unsigned short* zb    = (unsigned short*)(ws + 8 * MB);   // reuse qbT
  unsigned short* opart = (unsigned short*)(ws + 16 * MB);  // reuse kbT+vbT (16MB)
  float2* mlbuf         = (float2*)(ws + 0 * MB);           // reuse xb (512KB)

  k_cvt<<<dim3(4096), dim3(256), 0, stream>>>(x, xb);
  k_tab<<<dim3(512), dim3(256), 0, stream>>>(theta, sint, cost);
  k_tr<<<dim3(16, 64, 4), dim3(256), 0, stream>>>(q, qbT, 2048, 128);
  k_tr<<<dim3(16, 64, 4), dim3(256), 0, stream>>>(k, kbT, 2048, 128);
  k_tr<<<dim3(16, 64, 4), dim3(256), 0, stream>>>(v, vbT, 2048, 128);
  k_tr<<<dim3(1, 64, 64), dim3(256), 0, stream>>>(o, obT, 2048, 2048);
  k_proj<<<dim3(16, 16, 3), dim3(256), 0, stream>>>(xb, qbT, kbT, vbT, sint, cost, rq, rk, vst);
  k_attn4<<<dim3(512), dim3(256), 0, stream>>>(rq, rk, vst, opart, mlbuf);
  k_comb<<<dim3(2048), dim3(256), 0, stream>>>(opart, mlbuf, zb);
  k_out<<<dim3(16, 16), dim3(256), 0, stream>>>(zb, obT, out);
}

// Round 5
// 231.383 us; speedup vs baseline: 1.4312x; 1.0642x over previous
//
#include <hip/hip_runtime.h>

// ShrdMHAttention on MI355X (gfx950).
// cvt/transpose -> bf16 MFMA proj GEMM (+RoPE epilogue, attn-scale folded into q)
// -> causal flash attention (padded-LDS staged K/V, swapped QK^T, in-register
//    softmax, UNIFORM kv-chunks of <=10 tiles) -> combine -> output GEMM.
// Workspace: 0-30.5MB opart (post-proj; was xb/qbT/kbT/vbT) | 31MB mlbuf |
// 32MB obT | 40MB rq [reused: z after attn] | 48MB rk | 56MB vst | 64MB tables
// Pre-proj: 0MB xb | 8MB qbT | 16MB kbT | 24MB vbT

#define S_LEN   2048
#define D_MODEL 2048
#define NHEAD   16
#define DHEAD   128

using f32x4   = __attribute__((ext_vector_type(4))) float;
using f32x16  = __attribute__((ext_vector_type(16))) float;
using bf16x8  = __attribute__((ext_vector_type(8))) __bf16;

__device__ __forceinline__ unsigned short f2bf(float f) {
  unsigned int u = __builtin_bit_cast(unsigned int, f);
  u += 0x7fffu + ((u >> 16) & 1u);          // RNE
  return (unsigned short)(u >> 16);
}
__device__ __forceinline__ int chunks_of(int qt) { return (4 * qt + 13) / 10; } // ceil((4qt+4)/10)

// ---------- fp32 -> bf16 copy (x) ----------
__global__ void k_cvt(const float* __restrict__ in, unsigned short* __restrict__ out) {
  int i = (blockIdx.x * 256 + threadIdx.x) * 4;
  float4 v = *reinterpret_cast<const float4*>(in + i);
  ushort4 o; o.x = f2bf(v.x); o.y = f2bf(v.y); o.z = f2bf(v.z); o.w = f2bf(v.w);
  *reinterpret_cast<ushort4*>(out + i) = o;
}

// ---------- RoPE sin/cos tables ----------
__global__ void k_tab(const float* __restrict__ theta_p, float* __restrict__ sint,
                      float* __restrict__ cost) {
  int i = blockIdx.x * 256 + threadIdx.x;   // [0, 2048*64)
  int s = i >> 6, c = i & 63;
  float rate = theta_p[0] * (-(float)c / 64.0f);
  float sn, cs;
  sincosf((float)s * rate, &sn, &cs);
  sint[i] = sn; cost[i] = cs;
}

// ---------- transpose+convert: fp32 (B,R,C) -> bf16 (B,C,R) ----------
__global__ void k_tr(const float* __restrict__ in, unsigned short* __restrict__ out,
                     int R, int C) {
  __shared__ float t[32][33];
  int b = blockIdx.x, rt = blockIdx.y, ct = blockIdx.z;
  const float* ip = in + (size_t)b * R * C;
  unsigned short* op = out + (size_t)b * R * C;
  int tx = threadIdx.x & 31, ty = threadIdx.x >> 5;   // 32 x 8
  #pragma unroll
  for (int i = 0; i < 4; i++)
    t[ty + i * 8][tx] = ip[(size_t)(rt * 32 + ty + i * 8) * C + ct * 32 + tx];
  __syncthreads();
  #pragma unroll
  for (int i = 0; i < 4; i++)
    op[(size_t)(ct * 32 + ty + i * 8) * R + rt * 32 + tx] = f2bf(t[tx][ty + i * 8]);
}

// ---------- projection GEMM: C(128 x 128) = x-tile @ W_h^T, epilogue rope/scale ----------
__global__ __launch_bounds__(256) void k_proj(
    const unsigned short* __restrict__ xb,
    const unsigned short* __restrict__ wq, const unsigned short* __restrict__ wk,
    const unsigned short* __restrict__ wv,
    const float* __restrict__ sint, const float* __restrict__ cost,
    unsigned short* __restrict__ rq, unsigned short* __restrict__ rk,
    unsigned short* __restrict__ vst) {
  __shared__ uint4 ldsbuf[2048];            // 32 KB
  char* lds = (char*)ldsbuf;
  const int tid = threadIdx.x, l = tid & 63, w = tid >> 6;
  const int lr = l & 15, lk = l >> 4;
  const int s0 = blockIdx.x * 128;
  const int h = blockIdx.y, which = blockIdx.z;
  const unsigned short* wsel = which == 0 ? wq : (which == 1 ? wk : wv);
  const unsigned short* wbase = wsel + (size_t)h * DHEAD * D_MODEL;

  f32x4 acc[2][8] = {};

  for (int kt = 0; kt < D_MODEL; kt += 64) {
    #pragma unroll
    for (int j = 0; j < 4; j++) {
      int ci = tid + j * 256;
      int r = ci >> 3, c16 = ci & 7;
      int sw = (c16 ^ (r & 7)) * 16;
      bf16x8 av = *reinterpret_cast<const bf16x8*>(xb + (size_t)(s0 + r) * D_MODEL + kt + c16 * 8);
      *reinterpret_cast<bf16x8*>(lds + r * 128 + sw) = av;
      bf16x8 bv = *reinterpret_cast<const bf16x8*>(wbase + (size_t)r * D_MODEL + kt + c16 * 8);
      *reinterpret_cast<bf16x8*>(lds + 16384 + r * 128 + sw) = bv;
    }
    __syncthreads();
    #pragma unroll
    for (int kk = 0; kk < 2; kk++) {
      const int kb = kk * 64 + lk * 16;
      bf16x8 a[2], b[8];
      #pragma unroll
      for (int mf = 0; mf < 2; mf++) {
        int rr = w * 32 + mf * 16 + lr;
        a[mf] = *reinterpret_cast<const bf16x8*>(lds + rr * 128 + (kb ^ ((rr & 7) << 4)));
      }
      #pragma unroll
      for (int nf = 0; nf < 8; nf++) {
        int rn = nf * 16 + lr;
        b[nf] = *reinterpret_cast<const bf16x8*>(lds + 16384 + rn * 128 + (kb ^ ((rn & 7) << 4)));
      }
      #pragma unroll
      for (int mf = 0; mf < 2; mf++)
        #pragma unroll
        for (int nf = 0; nf < 8; nf++)
          acc[mf][nf] = __builtin_amdgcn_mfma_f32_16x16x32_bf16(a[mf], b[nf], acc[mf][nf], 0, 0, 0);
    }
    __syncthreads();
  }

  const float xscale = 0.022097086912079608f;             // 1/sqrt(2048)
  const float qsc = xscale * 0.08838834764831845f;        // * 1/sqrt(128) folded
  if (which < 2) {
    const float sc_out = (which == 0) ? qsc : xscale;
    unsigned short* dst = (which == 0 ? rq : rk) + (size_t)h * S_LEN * DHEAD;
    #pragma unroll
    for (int mf = 0; mf < 2; mf++) {
      #pragma unroll
      for (int nf = 0; nf < 4; nf++) {
        int c1 = nf * 16 + lr;
        #pragma unroll
        for (int rg = 0; rg < 4; rg++) {
          int srow = s0 + w * 32 + mf * 16 + lk * 4 + rg;
          float sn = sint[srow * 64 + c1], cs = cost[srow * 64 + c1];
          float x1 = acc[mf][nf][rg] * sc_out;
          float x2 = acc[mf][nf + 4][rg] * sc_out;
          dst[(size_t)srow * DHEAD + c1]      = f2bf(cs * x1 - sn * x2);
          dst[(size_t)srow * DHEAD + c1 + 64] = f2bf(sn * x1 + cs * x2);
        }
      }
    }
  } else {                                      // v: store transposed vst[h][c][s]
    unsigned short* dst = vst + (size_t)h * DHEAD * S_LEN;
    #pragma unroll
    for (int mf = 0; mf < 2; mf++) {
      int rbase = s0 + w * 32 + mf * 16 + lk * 4;
      #pragma unroll
      for (int nf = 0; nf < 8; nf++) {
        int c = nf * 16 + lr;
        ushort4 ov;
        ov.x = f2bf(acc[mf][nf][0] * xscale); ov.y = f2bf(acc[mf][nf][1] * xscale);
        ov.z = f2bf(acc[mf][nf][2] * xscale); ov.w = f2bf(acc[mf][nf][3] * xscale);
        *reinterpret_cast<ushort4*>(dst + (size_t)c * S_LEN + rbase) = ov;
      }
    }
  }
}

// ---------- causal flash attention v5: uniform kv-chunks, padded-LDS K/V ----------
// 976 blocks = 16h x 61 units; unit u -> (qt, chunk c of <=10 kv-tiles).
// 4 waves x 32 q-rows; KVBLK=32; K rows @272B, Vt rows @80B.
__global__ __launch_bounds__(256, 2) void k_attn5(
    const unsigned short* __restrict__ rq, const unsigned short* __restrict__ rk,
    const unsigned short* __restrict__ vst,
    unsigned short* __restrict__ opart, float2* __restrict__ mlbuf) {
  __shared__ uint4 ldsbuf[1184];            // 18944B: K @0 (8704), Vt @8704 (10240)
  char* lds = (char*)ldsbuf;
  const int tid = threadIdx.x, l = tid & 63, w = tid >> 6;
  const int hi = l >> 5, qcol = l & 31;
  const int b = blockIdx.x;
  const int h = b & 15;                     // head h -> XCD h&7 (K/V L2 locality)
  int u = b >> 4, qt = 0;
  while (u >= chunks_of(qt)) { u -= chunks_of(qt); qt++; }
  const int ntile = 4 * qt + 4;
  const int tbeg = u * 10;
  const int tend = (tbeg + 10 < ntile) ? tbeg + 10 : ntile;
  const int s0w = qt * 128 + w * 32;
  const int wlast = s0w + 31;
  const int dtile = s0w >> 5;               // diagonal tile index

  const unsigned short* rk_h  = rk  + (size_t)h * S_LEN * DHEAD;
  const unsigned short* vst_h = vst + (size_t)h * DHEAD * S_LEN;

  // Q fragments (B-operand of swapped QK^T), scales pre-folded in k_proj
  const unsigned short* qrow_p = rq + ((size_t)h * S_LEN + s0w + qcol) * DHEAD + hi * 8;
  bf16x8 qb[8];
  #pragma unroll
  for (int kk = 0; kk < 8; kk++)
    qb[kk] = *reinterpret_cast<const bf16x8*>(qrow_p + kk * 16);

  f32x16 O[4] = {};
  float mrow = -3.0e38f, lrow = 0.0f;

  uint4 kreg[2], vreg[2];
  {                                         // prefetch tile tbeg
    const int t0 = tbeg * 32;
    #pragma unroll
    for (int j = 0; j < 2; j++) {
      int ci = tid + j * 256;
      kreg[j] = *reinterpret_cast<const uint4*>(rk_h + (size_t)(t0 + (ci >> 4)) * DHEAD + (ci & 15) * 8);
      vreg[j] = *reinterpret_cast<const uint4*>(vst_h + (size_t)(ci >> 2) * S_LEN + t0 + (ci & 3) * 8);
    }
  }

  for (int t = tbeg; t < tend; t++) {
    __syncthreads();                        // prior tile's LDS reads done
    #pragma unroll
    for (int j = 0; j < 2; j++) {
      int ci = tid + j * 256;
      *reinterpret_cast<uint4*>(lds + (ci >> 4) * 272 + (ci & 15) * 16) = kreg[j];
      *reinterpret_cast<uint4*>(lds + 8704 + (ci >> 2) * 80 + (ci & 3) * 16) = vreg[j];
    }
    if (t + 1 < tend) {                     // T14: issue next tile's loads now
      const int t0n = (t + 1) * 32;
      #pragma unroll
      for (int j = 0; j < 2; j++) {
        int ci = tid + j * 256;
        kreg[j] = *reinterpret_cast<const uint4*>(rk_h + (size_t)(t0n + (ci >> 4)) * DHEAD + (ci & 15) * 8);
        vreg[j] = *reinterpret_cast<const uint4*>(vst_h + (size_t)(ci >> 2) * S_LEN + t0n + (ci & 3) * 8);
      }
    }
    __syncthreads();                        // staged tile visible
    const int tt0 = t * 32;
    if (tt0 <= wlast) {
      // --- QK^T: sc[kv(reg), q(lane)] ---
      f32x16 sc = {};
      #pragma unroll
      for (int kk = 0; kk < 8; kk++) {
        bf16x8 ka = *reinterpret_cast<const bf16x8*>(lds + qcol * 272 + kk * 32 + hi * 16);
        sc = __builtin_amdgcn_mfma_f32_32x32x16_bf16(ka, qb[kk], sc, 0, 0, 0);
      }
      float p[16];
      #pragma unroll
      for (int r = 0; r < 16; r++) p[r] = sc[r];
      if (t == dtile) {                     // diagonal tile: causal mask
        #pragma unroll
        for (int r = 0; r < 16; r++)
          if (((r & 3) + 8 * (r >> 2) + 4 * hi) > qcol) p[r] = -1.0e9f;
      }
      // --- row max (pairwise tree + one cross-half swap) ---
      float mx[8];
      #pragma unroll
      for (int i = 0; i < 8; i++) mx[i] = fmaxf(p[2 * i], p[2 * i + 1]);
      #pragma unroll
      for (int i = 0; i < 4; i++) mx[i] = fmaxf(mx[i], mx[i + 4]);
      mx[0] = fmaxf(mx[0], mx[2]); mx[1] = fmaxf(mx[1], mx[3]);
      float pmax = fmaxf(mx[0], mx[1]);
      pmax = fmaxf(pmax, __shfl_xor(pmax, 32, 64));
      // --- defer-max rescale ---
      if (__any(pmax > mrow + 8.0f)) {
        float mn = fmaxf(mrow, pmax);
        float sf = __expf(mrow - mn);
        lrow *= sf; mrow = mn;
        #pragma unroll
        for (int vc = 0; vc < 4; vc++)
          #pragma unroll
          for (int r = 0; r < 16; r++) O[vc][r] *= sf;
      }
      #pragma unroll
      for (int r = 0; r < 16; r++) p[r] = __expf(p[r] - mrow);
      float sm[8];
      #pragma unroll
      for (int i = 0; i < 8; i++) sm[i] = p[2 * i] + p[2 * i + 1];
      #pragma unroll
      for (int i = 0; i < 4; i++) sm[i] += sm[i + 4];
      float psum = (sm[0] + sm[1]) + (sm[2] + sm[3]);
      psum += __shfl_xor(psum, 32, 64);
      lrow += psum;
      // --- pack P -> bf16 B-frags (kv-chunks c=0,1 of 16) ---
      unsigned int pk[2][4], sw[2][4];
      #pragma unroll
      for (int c = 0; c < 2; c++)
        #pragma unroll
        for (int k = 0; k < 4; k++) {
          unsigned int r_;
          asm("v_cvt_pk_bf16_f32 %0, %1, %2" : "=v"(r_)
              : "v"(p[8 * c + 2 * k]), "v"(p[8 * c + 2 * k + 1]));
          pk[c][k] = r_;
          sw[c][k] = (unsigned int)__shfl_xor((int)r_, 32, 64);
        }
      bf16x8 pb[2];
      #pragma unroll
      for (int c = 0; c < 2; c++) {
        union { unsigned int u4[4]; bf16x8 v; } bw;
        bw.u4[0] = hi ? sw[c][2] : pk[c][0];
        bw.u4[1] = hi ? sw[c][3] : pk[c][1];
        bw.u4[2] = hi ? pk[c][2] : sw[c][0];
        bw.u4[3] = hi ? pk[c][3] : sw[c][1];
        pb[c] = bw.v;
      }
      // --- PV from LDS V^T ---
      #pragma unroll
      for (int vc = 0; vc < 4; vc++) {
        const char* vrow = lds + 8704 + (vc * 32 + qcol) * 80 + hi * 16;
        bf16x8 va0 = *reinterpret_cast<const bf16x8*>(vrow);
        bf16x8 va1 = *reinterpret_cast<const bf16x8*>(vrow + 32);
        O[vc] = __builtin_amdgcn_mfma_f32_32x32x16_bf16(va0, pb[0], O[vc], 0, 0, 0);
        O[vc] = __builtin_amdgcn_mfma_f32_32x32x16_bf16(va1, pb[1], O[vc], 0, 0, 0);
      }
    }
  }
  // --- write partial: opart[b][row][v] bf16 normalized, ml stats ---
  float inv = lrow > 0.0f ? 1.0f / lrow : 0.0f;
  unsigned short* op = opart + ((size_t)b * 128 + w * 32 + qcol) * DHEAD;
  #pragma unroll
  for (int vc = 0; vc < 4; vc++)
    #pragma unroll
    for (int g = 0; g < 4; g++) {
      int v0 = vc * 32 + 8 * g + 4 * hi;
      ushort4 ov;
      ov.x = f2bf(O[vc][4 * g + 0] * inv); ov.y = f2bf(O[vc][4 * g + 1] * inv);
      ov.z = f2bf(O[vc][4 * g + 2] * inv); ov.w = f2bf(O[vc][4 * g + 3] * inv);
      *reinterpret_cast<ushort4*>(op + v0) = ov;
    }
  if (l < 32)
    mlbuf[(size_t)b * 128 + w * 32 + l] = make_float2(mrow, lrow);
}

// ---------- combine up to 7 chunk partials per (h, q-row) ----------
__global__ void k_comb2(const unsigned short* __restrict__ opart,
                        const float2* __restrict__ mlbuf,
                        unsigned short* __restrict__ z) {
  int g = blockIdx.x * 256 + threadIdx.x;     // 16h * 2048q * 16vg
  int vg = g & 15, q = (g >> 4) & 2047, h = g >> 15;
  int qt = q >> 7, r = q & 127;
  int base = 0;
  for (int j = 0; j < qt; j++) base += chunks_of(j);
  const int nc = chunks_of(qt);               // 1..7
  float m = -3.0e38f;
  float2 ml[7];
  #pragma unroll
  for (int cc = 0; cc < 7; cc++)
    if (cc < nc) {
      ml[cc] = mlbuf[(size_t)((base + cc) * 16 + h) * 128 + r];
      m = fmaxf(m, ml[cc].x);
    }
  float wts[7], wsum = 0.0f;
  #pragma unroll
  for (int cc = 0; cc < 7; cc++)
    if (cc < nc) {
      float wv = ml[cc].y > 0.0f ? ml[cc].y * __expf(ml[cc].x - m) : 0.0f;
      wts[cc] = wv; wsum += wv;
    }
  float wi = 1.0f / wsum;
  float acc[8] = {};
  #pragma unroll
  for (int cc = 0; cc < 7; cc++)
    if (cc < nc && wts[cc] > 0.0f) {
      float wv = wts[cc] * wi;
      bf16x8 v = *reinterpret_cast<const bf16x8*>(
          opart + ((size_t)((base + cc) * 16 + h) * 128 + r) * DHEAD + vg * 8);
      #pragma unroll
      for (int j = 0; j < 8; j++) acc[j] += wv * (float)v[j];
    }
  unsigned short* zp = z + (size_t)q * D_MODEL + h * DHEAD + vg * 8;
  ushort4 lo, hi4;
  lo.x = f2bf(acc[0]); lo.y = f2bf(acc[1]); lo.z = f2bf(acc[2]); lo.w = f2bf(acc[3]);
  hi4.x = f2bf(acc[4]); hi4.y = f2bf(acc[5]); hi4.z = f2bf(acc[6]); hi4.w = f2bf(acc[7]);
  *reinterpret_cast<ushort4*>(zp) = lo;
  *reinterpret_cast<ushort4*>(zp + 4) = hi4;
}

// ---------- output GEMM: out(S,D) = z(S,2048) @ obT^T * out_scale ----------
__global__ __launch_bounds__(256) void k_out(
    const unsigned short* __restrict__ zb, const unsigned short* __restrict__ obT,
    float* __restrict__ out) {
  __shared__ uint4 ldsbuf[2048];
  char* lds = (char*)ldsbuf;
  const int tid = threadIdx.x, l = tid & 63, w = tid >> 6;
  const int lr = l & 15, lk = l >> 4;
  const int s0 = blockIdx.x * 128, n0 = blockIdx.y * 128;
  const int wm = w >> 1, wn = w & 1;
  f32x4 acc[4][4] = {};
  for (int kt = 0; kt < D_MODEL; kt += 64) {
    #pragma unroll
    for (int j = 0; j < 4; j++) {
      int ci = tid + j * 256;
      int r = ci >> 3, c16 = ci & 7;
      int sw = (c16 ^ (r & 7)) * 16;
      bf16x8 av = *reinterpret_cast<const bf16x8*>(zb + (size_t)(s0 + r) * D_MODEL + kt + c16 * 8);
      *reinterpret_cast<bf16x8*>(lds + r * 128 + sw) = av;
      bf16x8 bv = *reinterpret_cast<const bf16x8*>(obT + (size_t)(n0 + r) * D_MODEL + kt + c16 * 8);
      *reinterpret_cast<bf16x8*>(lds + 16384 + r * 128 + sw) = bv;
    }
    __syncthreads();
    #pragma unroll
    for (int kk = 0; kk < 2; kk++) {
      const int kb = kk * 64 + lk * 16;
      bf16x8 a[4], b[4];
      #pragma unroll
      for (int mf = 0; mf < 4; mf++) {
        int rr = wm * 64 + mf * 16 + lr;
        a[mf] = *reinterpret_cast<const bf16x8*>(lds + rr * 128 + (kb ^ ((rr & 7) << 4)));
      }
      #pragma unroll
      for (int nf = 0; nf < 4; nf++) {
        int rn = wn * 64 + nf * 16 + lr;
        b[nf] = *reinterpret_cast<const bf16x8*>(lds + 16384 + rn * 128 + (kb ^ ((rn & 7) << 4)));
      }
      #pragma unroll
      for (int mf = 0; mf < 4; mf++)
        #pragma unroll
        for (int nf = 0; nf < 4; nf++)
          acc[mf][nf] = __builtin_amdgcn_mfma_f32_16x16x32_bf16(a[mf], b[nf], acc[mf][nf], 0, 0, 0);
    }
    __syncthreads();
  }
  const float osc = 0.022097086912079608f;      // 1/sqrt(2048)
  #pragma unroll
  for (int mf = 0; mf < 4; mf++)
    #pragma unroll
    for (int nf = 0; nf < 4; nf++)
      #pragma unroll
      for (int rg = 0; rg < 4; rg++)
        out[(size_t)(s0 + wm * 64 + mf * 16 + lk * 4 + rg) * D_MODEL + n0 + wn * 64 + nf * 16 + lr]
            = acc[mf][nf][rg] * osc;
}

extern "C" void kernel_launch(void* const* d_in, const int* in_sizes, int n_in,
                              void* d_out, int out_size, void* d_ws, size_t ws_size,
                              hipStream_t stream) {
  const float* x = (const float*)d_in[0];
  const float* q = (const float*)d_in[1];
  const float* k = (const float*)d_in[2];
  const float* v = (const float*)d_in[3];
  const float* o = (const float*)d_in[4];
  const float* theta = (const float*)d_in[5];
  float* out = (float*)d_out;

  char* ws = (char*)d_ws;
  const size_t MB = 1u << 20;
  unsigned short* xb  = (unsigned short*)(ws + 0 * MB);
  unsigned short* qbT = (unsigned short*)(ws + 8 * MB);
  unsigned short* kbT = (unsigned short*)(ws + 16 * MB);
  unsigned short* vbT = (unsigned short*)(ws + 24 * MB);
  unsigned short* obT = (unsigned short*)(ws + 32 * MB);
  unsigned short* rq  = (unsigned short*)(ws + 40 * MB);
  unsigned short* rk  = (unsigned short*)(ws + 48 * MB);
  unsigned short* vst = (unsigned short*)(ws + 56 * MB);
  float* sint = (float*)(ws + 64 * MB);
  float* cost = (float*)(ws + 64 * MB + 512 * 1024);
  unsigned short* opart = (unsigned short*)(ws + 0 * MB);   // 976*128*128*2B = 30.5MB
  float2* mlbuf         = (float2*)(ws + 31 * MB);          // 976*128*8B ~ 1MB
  unsigned short* zb    = (unsigned short*)(ws + 40 * MB);  // reuse rq (dead after attn)

  k_cvt<<<dim3(4096), dim3(256), 0, stream>>>(x, xb);
  k_tab<<<dim3(512), dim3(256), 0, stream>>>(theta, sint, cost);
  k_tr<<<dim3(16, 64, 4), dim3(256), 0, stream>>>(q, qbT, 2048, 128);
  k_tr<<<dim3(16, 64, 4), dim3(256), 0, stream>>>(k, kbT, 2048, 128);
  k_tr<<<dim3(16, 64, 4), dim3(256), 0, stream>>>(v, vbT, 2048, 128);
  k_tr<<<dim3(1, 64, 64), dim3(256), 0, stream>>>(o, obT, 2048, 2048);
  k_proj<<<dim3(16, 16, 3), dim3(256), 0, stream>>>(xb, qbT, kbT, vbT, sint, cost, rq, rk, vst);
  k_attn5<<<dim3(976), dim3(256), 0, stream>>>(rq, rk, vst, opart, mlbuf);
  k_comb2<<<dim3(2048), dim3(256), 0, stream>>>(opart, mlbuf, zb);
  k_out<<<dim3(16, 16), dim3(256), 0, stream>>>(zb, obT, out);
}

// Round 6
// 228.451 us; speedup vs baseline: 1.4496x; 1.0128x over previous
//
#include <hip/hip_runtime.h>

// ShrdMHAttention on MI355X (gfx950).
// cvt/transpose -> ONE merged bf16 MFMA proj GEMM (M=2048,N=6144, global_load_lds
// staging, XCD-swizzled grid, RoPE epilogue) -> causal flash attention (padded-LDS
// K/V, swapped QK^T, in-register softmax, uniform kv-chunks) -> combine -> output
// GEMM (global_load_lds staging).
// Workspace: 0-30.5MB opart (post-proj; was xb/qbT/kbT/vbT) | 31MB mlbuf |
// 32MB obT | 40MB rq [reused: z after attn] | 48MB rk | 56MB vst | 64MB tables
// Pre-proj: 0MB xb | 8MB qbT | 16MB kbT | 24MB vbT  (qbT..vbT = merged W^T[6144][2048])

#define S_LEN   2048
#define D_MODEL 2048
#define NHEAD   16
#define DHEAD   128

using f32x4   = __attribute__((ext_vector_type(4))) float;
using f32x16  = __attribute__((ext_vector_type(16))) float;
using bf16x8  = __attribute__((ext_vector_type(8))) __bf16;

__device__ __forceinline__ unsigned short f2bf(float f) {
  unsigned int u = __builtin_bit_cast(unsigned int, f);
  u += 0x7fffu + ((u >> 16) & 1u);          // RNE
  return (unsigned short)(u >> 16);
}
__device__ __forceinline__ int chunks_of(int qt) { return (4 * qt + 13) / 10; } // ceil((4qt+4)/10)

// async global->LDS, 16B per lane. LDS dest is wave-uniform base + lane*16.
__device__ __forceinline__ void gl_lds16(const unsigned short* g, char* l) {
  __builtin_amdgcn_global_load_lds(
      (const __attribute__((address_space(1))) unsigned int*)g,
      (__attribute__((address_space(3))) unsigned int*)l, 16, 0, 0);
}

// ---------- fp32 -> bf16 copy (x) ----------
__global__ void k_cvt(const float* __restrict__ in, unsigned short* __restrict__ out) {
  int i = (blockIdx.x * 256 + threadIdx.x) * 4;
  float4 v = *reinterpret_cast<const float4*>(in + i);
  ushort4 o; o.x = f2bf(v.x); o.y = f2bf(v.y); o.z = f2bf(v.z); o.w = f2bf(v.w);
  *reinterpret_cast<ushort4*>(out + i) = o;
}

// ---------- RoPE sin/cos tables ----------
__global__ void k_tab(const float* __restrict__ theta_p, float* __restrict__ sint,
                      float* __restrict__ cost) {
  int i = blockIdx.x * 256 + threadIdx.x;   // [0, 2048*64)
  int s = i >> 6, c = i & 63;
  float rate = theta_p[0] * (-(float)c / 64.0f);
  float sn, cs;
  sincosf((float)s * rate, &sn, &cs);
  sint[i] = sn; cost[i] = cs;
}

// ---------- transpose+convert: fp32 (B,R,C) -> bf16 (B,C,R) ----------
__global__ void k_tr(const float* __restrict__ in, unsigned short* __restrict__ out,
                     int R, int C) {
  __shared__ float t[32][33];
  int b = blockIdx.x, rt = blockIdx.y, ct = blockIdx.z;
  const float* ip = in + (size_t)b * R * C;
  unsigned short* op = out + (size_t)b * R * C;
  int tx = threadIdx.x & 31, ty = threadIdx.x >> 5;   // 32 x 8
  #pragma unroll
  for (int i = 0; i < 4; i++)
    t[ty + i * 8][tx] = ip[(size_t)(rt * 32 + ty + i * 8) * C + ct * 32 + tx];
  __syncthreads();
  #pragma unroll
  for (int i = 0; i < 4; i++)
    op[(size_t)(ct * 32 + ty + i * 8) * R + rt * 32 + tx] = f2bf(t[tx][ty + i * 8]);
}

// ---------- merged projection GEMM: C(2048 x 6144) = xb @ W^T, RoPE epilogue ----------
// 768 blocks (XCD-swizzled) = 16 s-tiles x 48 n-tiles; each n-tile = one
// (tensor, head). 4 waves x (32 rows x 128 cols); global_load_lds staging into
// LDS with XOR-swizzled placement (source-side permutation, linear dest).
__global__ __launch_bounds__(256) void k_proj2(
    const unsigned short* __restrict__ xb, const unsigned short* __restrict__ wT,
    const float* __restrict__ sint, const float* __restrict__ cost,
    unsigned short* __restrict__ rq, unsigned short* __restrict__ rk,
    unsigned short* __restrict__ vst) {
  __shared__ char lds[32768];               // A[128][64] @0, B[128][64] @16K
  const int tid = threadIdx.x, l = tid & 63, w = tid >> 6;
  const int lr = l & 15, lk = l >> 4;
  const int orig = blockIdx.x;
  const int wg = (orig & 7) * 96 + (orig >> 3);   // XCD-contiguous remap (768%8==0)
  const int bx = wg & 15, by = wg >> 4;     // s-tile, n-tile
  const int s0 = bx * 128;
  const int h = by & 15, which = by >> 4;   // n-tile -> (head, q/k/v)
  const unsigned short* bbase = wT + (size_t)by * 128 * D_MODEL;

  f32x4 acc[2][8] = {};

  for (int kt = 0; kt < D_MODEL; kt += 64) {
    #pragma unroll
    for (int j = 0; j < 4; j++) {           // stage A+B: linear LDS, swizzled source
      int ci = (j * 4 + w) * 64 + l;        // 0..1023
      int r = ci >> 3, c8 = ci & 7;
      int csrc = (c8 ^ (r & 7)) * 8;
      gl_lds16(xb + (size_t)(s0 + r) * D_MODEL + kt + csrc,
               lds + (j * 4 + w) * 1024 + (l & 63) * 16);
      gl_lds16(bbase + (size_t)r * D_MODEL + kt + csrc,
               lds + 16384 + (j * 4 + w) * 1024 + (l & 63) * 16);
    }
    asm volatile("s_waitcnt vmcnt(0)" ::: "memory");
    __syncthreads();
    #pragma unroll
    for (int kk = 0; kk < 2; kk++) {
      const int kb = kk * 64 + lk * 16;
      bf16x8 a[2], b[8];
      #pragma unroll
      for (int mf = 0; mf < 2; mf++) {
        int rr = w * 32 + mf * 16 + lr;
        a[mf] = *reinterpret_cast<const bf16x8*>(lds + rr * 128 + (kb ^ ((rr & 7) << 4)));
      }
      #pragma unroll
      for (int nf = 0; nf < 8; nf++) {
        int rn = nf * 16 + lr;
        b[nf] = *reinterpret_cast<const bf16x8*>(lds + 16384 + rn * 128 + (kb ^ ((rn & 7) << 4)));
      }
      #pragma unroll
      for (int mf = 0; mf < 2; mf++)
        #pragma unroll
        for (int nf = 0; nf < 8; nf++)
          acc[mf][nf] = __builtin_amdgcn_mfma_f32_16x16x32_bf16(a[mf], b[nf], acc[mf][nf], 0, 0, 0);
    }
    __syncthreads();
  }

  const float xscale = 0.022097086912079608f;             // 1/sqrt(2048)
  const float qsc = xscale * 0.08838834764831845f;        // * 1/sqrt(128) folded
  if (which < 2) {
    const float sc_out = (which == 0) ? qsc : xscale;
    unsigned short* dst = (which == 0 ? rq : rk) + (size_t)h * S_LEN * DHEAD;
    #pragma unroll
    for (int mf = 0; mf < 2; mf++) {
      #pragma unroll
      for (int nf = 0; nf < 4; nf++) {
        int c1 = nf * 16 + lr;
        #pragma unroll
        for (int rg = 0; rg < 4; rg++) {
          int srow = s0 + w * 32 + mf * 16 + lk * 4 + rg;
          float sn = sint[srow * 64 + c1], cs = cost[srow * 64 + c1];
          float x1 = acc[mf][nf][rg] * sc_out;
          float x2 = acc[mf][nf + 4][rg] * sc_out;
          dst[(size_t)srow * DHEAD + c1]      = f2bf(cs * x1 - sn * x2);
          dst[(size_t)srow * DHEAD + c1 + 64] = f2bf(sn * x1 + cs * x2);
        }
      }
    }
  } else {                                      // v: store transposed vst[h][c][s]
    unsigned short* dst = vst + (size_t)h * DHEAD * S_LEN;
    #pragma unroll
    for (int mf = 0; mf < 2; mf++) {
      int rbase = s0 + w * 32 + mf * 16 + lk * 4;
      #pragma unroll
      for (int nf = 0; nf < 8; nf++) {
        int c = nf * 16 + lr;
        ushort4 ov;
        ov.x = f2bf(acc[mf][nf][0] * xscale); ov.y = f2bf(acc[mf][nf][1] * xscale);
        ov.z = f2bf(acc[mf][nf][2] * xscale); ov.w = f2bf(acc[mf][nf][3] * xscale);
        *reinterpret_cast<ushort4*>(dst + (size_t)c * S_LEN + rbase) = ov;
      }
    }
  }
}

// ---------- causal flash attention v5: uniform kv-chunks, padded-LDS K/V ----------
// 976 blocks = 16h x 61 units; unit u -> (qt, chunk c of <=10 kv-tiles).
// 4 waves x 32 q-rows; KVBLK=32; K rows @272B, Vt rows @80B.
__global__ __launch_bounds__(256, 2) void k_attn5(
    const unsigned short* __restrict__ rq, const unsigned short* __restrict__ rk,
    const unsigned short* __restrict__ vst,
    unsigned short* __restrict__ opart, float2* __restrict__ mlbuf) {
  __shared__ uint4 ldsbuf[1184];            // 18944B: K @0 (8704), Vt @8704 (10240)
  char* lds = (char*)ldsbuf;
  const int tid = threadIdx.x, l = tid & 63, w = tid >> 6;
  const int hi = l >> 5, qcol = l & 31;
  const int b = blockIdx.x;
  const int h = b & 15;                     // head h -> XCD h&7 (K/V L2 locality)
  int u = b >> 4, qt = 0;
  while (u >= chunks_of(qt)) { u -= chunks_of(qt); qt++; }
  const int ntile = 4 * qt + 4;
  const int tbeg = u * 10;
  const int tend = (tbeg + 10 < ntile) ? tbeg + 10 : ntile;
  const int s0w = qt * 128 + w * 32;
  const int wlast = s0w + 31;
  const int dtile = s0w >> 5;               // diagonal tile index

  const unsigned short* rk_h  = rk  + (size_t)h * S_LEN * DHEAD;
  const unsigned short* vst_h = vst + (size_t)h * DHEAD * S_LEN;

  // Q fragments (B-operand of swapped QK^T), scales pre-folded in k_proj
  const unsigned short* qrow_p = rq + ((size_t)h * S_LEN + s0w + qcol) * DHEAD + hi * 8;
  bf16x8 qb[8];
  #pragma unroll
  for (int kk = 0; kk < 8; kk++)
    qb[kk] = *reinterpret_cast<const bf16x8*>(qrow_p + kk * 16);

  f32x16 O[4] = {};
  float mrow = -3.0e38f, lrow = 0.0f;

  uint4 kreg[2], vreg[2];
  {                                         // prefetch tile tbeg
    const int t0 = tbeg * 32;
    #pragma unroll
    for (int j = 0; j < 2; j++) {
      int ci = tid + j * 256;
      kreg[j] = *reinterpret_cast<const uint4*>(rk_h + (size_t)(t0 + (ci >> 4)) * DHEAD + (ci & 15) * 8);
      vreg[j] = *reinterpret_cast<const uint4*>(vst_h + (size_t)(ci >> 2) * S_LEN + t0 + (ci & 3) * 8);
    }
  }

  for (int t = tbeg; t < tend; t++) {
    __syncthreads();                        // prior tile's LDS reads done
    #pragma unroll
    for (int j = 0; j < 2; j++) {
      int ci = tid + j * 256;
      *reinterpret_cast<uint4*>(lds + (ci >> 4) * 272 + (ci & 15) * 16) = kreg[j];
      *reinterpret_cast<uint4*>(lds + 8704 + (ci >> 2) * 80 + (ci & 3) * 16) = vreg[j];
    }
    if (t + 1 < tend) {                     // T14: issue next tile's loads now
      const int t0n = (t + 1) * 32;
      #pragma unroll
      for (int j = 0; j < 2; j++) {
        int ci = tid + j * 256;
        kreg[j] = *reinterpret_cast<const uint4*>(rk_h + (size_t)(t0n + (ci >> 4)) * DHEAD + (ci & 15) * 8);
        vreg[j] = *reinterpret_cast<const uint4*>(vst_h + (size_t)(ci >> 2) * S_LEN + t0n + (ci & 3) * 8);
      }
    }
    __syncthreads();                        // staged tile visible
    const int tt0 = t * 32;
    if (tt0 <= wlast) {
      // --- QK^T: sc[kv(reg), q(lane)] ---
      f32x16 sc = {};
      #pragma unroll
      for (int kk = 0; kk < 8; kk++) {
        bf16x8 ka = *reinterpret_cast<const bf16x8*>(lds + qcol * 272 + kk * 32 + hi * 16);
        sc = __builtin_amdgcn_mfma_f32_32x32x16_bf16(ka, qb[kk], sc, 0, 0, 0);
      }
      float p[16];
      #pragma unroll
      for (int r = 0; r < 16; r++) p[r] = sc[r];
      if (t == dtile) {                     // diagonal tile: causal mask
        #pragma unroll
        for (int r = 0; r < 16; r++)
          if (((r & 3) + 8 * (r >> 2) + 4 * hi) > qcol) p[r] = -1.0e9f;
      }
      // --- row max (pairwise tree + one cross-half swap) ---
      float mx[8];
      #pragma unroll
      for (int i = 0; i < 8; i++) mx[i] = fmaxf(p[2 * i], p[2 * i + 1]);
      #pragma unroll
      for (int i = 0; i < 4; i++) mx[i] = fmaxf(mx[i], mx[i + 4]);
      mx[0] = fmaxf(mx[0], mx[2]); mx[1] = fmaxf(mx[1], mx[3]);
      float pmax = fmaxf(mx[0], mx[1]);
      pmax = fmaxf(pmax, __shfl_xor(pmax, 32, 64));
      // --- defer-max rescale ---
      if (__any(pmax > mrow + 8.0f)) {
        float mn = fmaxf(mrow, pmax);
        float sf = __expf(mrow - mn);
        lrow *= sf; mrow = mn;
        #pragma unroll
        for (int vc = 0; vc < 4; vc++)
          #pragma unroll
          for (int r = 0; r < 16; r++) O[vc][r] *= sf;
      }
      #pragma unroll
      for (int r = 0; r < 16; r++) p[r] = __expf(p[r] - mrow);
      float sm[8];
      #pragma unroll
      for (int i = 0; i < 8; i++) sm[i] = p[2 * i] + p[2 * i + 1];
      #pragma unroll
      for (int i = 0; i < 4; i++) sm[i] += sm[i + 4];
      float psum = (sm[0] + sm[1]) + (sm[2] + sm[3]);
      psum += __shfl_xor(psum, 32, 64);
      lrow += psum;
      // --- pack P -> bf16 B-frags (kv-chunks c=0,1 of 16) ---
      unsigned int pk[2][4], sw[2][4];
      #pragma unroll
      for (int c = 0; c < 2; c++)
        #pragma unroll
        for (int k = 0; k < 4; k++) {
          unsigned int r_;
          asm("v_cvt_pk_bf16_f32 %0, %1, %2" : "=v"(r_)
              : "v"(p[8 * c + 2 * k]), "v"(p[8 * c + 2 * k + 1]));
          pk[c][k] = r_;
          sw[c][k] = (unsigned int)__shfl_xor((int)r_, 32, 64);
        }
      bf16x8 pb[2];
      #pragma unroll
      for (int c = 0; c < 2; c++) {
        union { unsigned int u4[4]; bf16x8 v; } bw;
        bw.u4[0] = hi ? sw[c][2] : pk[c][0];
        bw.u4[1] = hi ? sw[c][3] : pk[c][1];
        bw.u4[2] = hi ? pk[c][2] : sw[c][0];
        bw.u4[3] = hi ? pk[c][3] : sw[c][1];
        pb[c] = bw.v;
      }
      // --- PV from LDS V^T ---
      #pragma unroll
      for (int vc = 0; vc < 4; vc++) {
        const char* vrow = lds + 8704 + (vc * 32 + qcol) * 80 + hi * 16;
        bf16x8 va0 = *reinterpret_cast<const bf16x8*>(vrow);
        bf16x8 va1 = *reinterpret_cast<const bf16x8*>(vrow + 32);
        O[vc] = __builtin_amdgcn_mfma_f32_32x32x16_bf16(va0, pb[0], O[vc], 0, 0, 0);
        O[vc] = __builtin_amdgcn_mfma_f32_32x32x16_bf16(va1, pb[1], O[vc], 0, 0, 0);
      }
    }
  }
  // --- write partial: opart[b][row][v] bf16 normalized, ml stats ---
  float inv = lrow > 0.0f ? 1.0f / lrow : 0.0f;
  unsigned short* op = opart + ((size_t)b * 128 + w * 32 + qcol) * DHEAD;
  #pragma unroll
  for (int vc = 0; vc < 4; vc++)
    #pragma unroll
    for (int g = 0; g < 4; g++) {
      int v0 = vc * 32 + 8 * g + 4 * hi;
      ushort4 ov;
      ov.x = f2bf(O[vc][4 * g + 0] * inv); ov.y = f2bf(O[vc][4 * g + 1] * inv);
      ov.z = f2bf(O[vc][4 * g + 2] * inv); ov.w = f2bf(O[vc][4 * g + 3] * inv);
      *reinterpret_cast<ushort4*>(op + v0) = ov;
    }
  if (l < 32)
    mlbuf[(size_t)b * 128 + w * 32 + l] = make_float2(mrow, lrow);
}

// ---------- combine up to 7 chunk partials per (h, q-row) ----------
__global__ void k_comb2(const unsigned short* __restrict__ opart,
                        const float2* __restrict__ mlbuf,
                        unsigned short* __restrict__ z) {
  int g = blockIdx.x * 256 + threadIdx.x;     // 16h * 2048q * 16vg
  int vg = g & 15, q = (g >> 4) & 2047, h = g >> 15;
  int qt = q >> 7, r = q & 127;
  int base = 0;
  for (int j = 0; j < qt; j++) base += chunks_of(j);
  const int nc = chunks_of(qt);               // 1..7
  float m = -3.0e38f;
  float2 ml[7];
  #pragma unroll
  for (int cc = 0; cc < 7; cc++)
    if (cc < nc) {
      ml[cc] = mlbuf[(size_t)((base + cc) * 16 + h) * 128 + r];
      m = fmaxf(m, ml[cc].x);
    }
  float wts[7], wsum = 0.0f;
  #pragma unroll
  for (int cc = 0; cc < 7; cc++)
    if (cc < nc) {
      float wv = ml[cc].y > 0.0f ? ml[cc].y * __expf(ml[cc].x - m) : 0.0f;
      wts[cc] = wv; wsum += wv;
    }
  float wi = 1.0f / wsum;
  float acc[8] = {};
  #pragma unroll
  for (int cc = 0; cc < 7; cc++)
    if (cc < nc && wts[cc] > 0.0f) {
      float wv = wts[cc] * wi;
      bf16x8 v = *reinterpret_cast<const bf16x8*>(
          opart + ((size_t)((base + cc) * 16 + h) * 128 + r) * DHEAD + vg * 8);
      #pragma unroll
      for (int j = 0; j < 8; j++) acc[j] += wv * (float)v[j];
    }
  unsigned short* zp = z + (size_t)q * D_MODEL + h * DHEAD + vg * 8;
  ushort4 lo, hi4;
  lo.x = f2bf(acc[0]); lo.y = f2bf(acc[1]); lo.z = f2bf(acc[2]); lo.w = f2bf(acc[3]);
  hi4.x = f2bf(acc[4]); hi4.y = f2bf(acc[5]); hi4.z = f2bf(acc[6]); hi4.w = f2bf(acc[7]);
  *reinterpret_cast<ushort4*>(zp) = lo;
  *reinterpret_cast<ushort4*>(zp + 4) = hi4;
}

// ---------- output GEMM: out(S,D) = z(S,2048) @ obT^T * out_scale ----------
// 256 blocks (XCD-swizzled); global_load_lds staging like k_proj2.
__global__ __launch_bounds__(256) void k_out2(
    const unsigned short* __restrict__ zb, const unsigned short* __restrict__ obT,
    float* __restrict__ out) {
  __shared__ char lds[32768];
  const int tid = threadIdx.x, l = tid & 63, w = tid >> 6;
  const int lr = l & 15, lk = l >> 4;
  const int orig = blockIdx.x;
  const int wg = (orig & 7) * 32 + (orig >> 3);   // 256%8==0, bijective
  const int bx = wg & 15, by = wg >> 4;
  const int s0 = bx * 128, n0 = by * 128;
  const int wm = w >> 1, wn = w & 1;
  f32x4 acc[4][4] = {};
  for (int kt = 0; kt < D_MODEL; kt += 64) {
    #pragma unroll
    for (int j = 0; j < 4; j++) {
      int ci = (j * 4 + w) * 64 + l;
      int r = ci >> 3, c8 = ci & 7;
      int csrc = (c8 ^ (r & 7)) * 8;
      gl_lds16(zb + (size_t)(s0 + r) * D_MODEL + kt + csrc,
               lds + (j * 4 + w) * 1024 + (l & 63) * 16);
      gl_lds16(obT + (size_t)(n0 + r) * D_MODEL + kt + csrc,
               lds + 16384 + (j * 4 + w) * 1024 + (l & 63) * 16);
    }
    asm volatile("s_waitcnt vmcnt(0)" ::: "memory");
    __syncthreads();
    #pragma unroll
    for (int kk = 0; kk < 2; kk++) {
      const int kb = kk * 64 + lk * 16;
      bf16x8 a[4], b[4];
      #pragma unroll
      for (int mf = 0; mf < 4; mf++) {
        int rr = wm * 64 + mf * 16 + lr;
        a[mf] = *reinterpret_cast<const bf16x8*>(lds + rr * 128 + (kb ^ ((rr & 7) << 4)));
      }
      #pragma unroll
      for (int nf = 0; nf < 4; nf++) {
        int rn = wn * 64 + nf * 16 + lr;
        b[nf] = *reinterpret_cast<const bf16x8*>(lds + 16384 + rn * 128 + (kb ^ ((rn & 7) << 4)));
      }
      #pragma unroll
      for (int mf = 0; mf < 4; mf++)
        #pragma unroll
        for (int nf = 0; nf < 4; nf++)
          acc[mf][nf] = __builtin_amdgcn_mfma_f32_16x16x32_bf16(a[mf], b[nf], acc[mf][nf], 0, 0, 0);
    }
    __syncthreads();
  }
  const float osc = 0.022097086912079608f;      // 1/sqrt(2048)
  #pragma unroll
  for (int mf = 0; mf < 4; mf++)
    #pragma unroll
    for (int nf = 0; nf < 4; nf++)
      #pragma unroll
      for (int rg = 0; rg < 4; rg++)
        out[(size_t)(s0 + wm * 64 + mf * 16 + lk * 4 + rg) * D_MODEL + n0 + wn * 64 + nf * 16 + lr]
            = acc[mf][nf][rg] * osc;
}

extern "C" void kernel_launch(void* const* d_in, const int* in_sizes, int n_in,
                              void* d_out, int out_size, void* d_ws, size_t ws_size,
                              hipStream_t stream) {
  const float* x = (const float*)d_in[0];
  const float* q = (const float*)d_in[1];
  const float* k = (const float*)d_in[2];
  const float* v = (const float*)d_in[3];
  const float* o = (const float*)d_in[4];
  const float* theta = (const float*)d_in[5];
  float* out = (float*)d_out;

  char* ws = (char*)d_ws;
  const size_t MB = 1u << 20;
  unsigned short* xb  = (unsigned short*)(ws + 0 * MB);
  unsigned short* qbT = (unsigned short*)(ws + 8 * MB);   // merged W^T[6144][2048] start
  unsigned short* kbT = (unsigned short*)(ws + 16 * MB);
  unsigned short* vbT = (unsigned short*)(ws + 24 * MB);
  unsigned short* obT = (unsigned short*)(ws + 32 * MB);
  unsigned short* rq  = (unsigned short*)(ws + 40 * MB);
  unsigned short* rk  = (unsigned short*)(ws + 48 * MB);
  unsigned short* vst = (unsigned short*)(ws + 56 * MB);
  float* sint = (float*)(ws + 64 * MB);
  float* cost = (float*)(ws + 64 * MB + 512 * 1024);
  unsigned short* opart = (unsigned short*)(ws + 0 * MB);   // 976*128*128*2B = 30.5MB
  float2* mlbuf         = (float2*)(ws + 31 * MB);          // 976*128*8B ~ 1MB
  unsigned short* zb    = (unsigned short*)(ws + 40 * MB);  // reuse rq (dead after attn)

  k_cvt<<<dim3(4096), dim3(256), 0, stream>>>(x, xb);
  k_tab<<<dim3(512), dim3(256), 0, stream>>>(theta, sint, cost);
  k_tr<<<dim3(16, 64, 4), dim3(256), 0, stream>>>(q, qbT, 2048, 128);
  k_tr<<<dim3(16, 64, 4), dim3(256), 0, stream>>>(k, kbT, 2048, 128);
  k_tr<<<dim3(16, 64, 4), dim3(256), 0, stream>>>(v, vbT, 2048, 128);
  k_tr<<<dim3(1, 64, 64), dim3(256), 0, stream>>>(o, obT, 2048, 2048);
  k_proj2<<<dim3(768), dim3(256), 0, stream>>>(xb, qbT, sint, cost, rq, rk, vst);
  k_attn5<<<dim3(976), dim3(256), 0, stream>>>(rq, rk, vst, opart, mlbuf);
  k_comb2<<<dim3(2048), dim3(256), 0, stream>>>(opart, mlbuf, zb);
  k_out2<<<dim3(256), dim3(256), 0, stream>>>(zb, obT, out);
}

// Round 7
// 200.483 us; speedup vs baseline: 1.6518x; 1.1395x over previous
//
#include <hip/hip_runtime.h>

// ShrdMHAttention on MI355X (gfx950).
// cvt/transpose -> merged proj GEMM (2-phase dbuf, counted vmcnt, gl_lds staging,
// RoPE epilogue) -> causal flash attention (padded-LDS K/V, swapped QK^T,
// in-register softmax, uniform kv-chunks) -> combine -> output GEMM (same dbuf).
// Workspace: 0-30.5MB opart | 31MB mlbuf | 32MB obT | 40MB rq[->z] | 48MB rk |
// 56MB vst | 64MB tables.  Pre-proj: 0MB xb | 8..32MB merged W^T[6144][2048]

#define S_LEN   2048
#define D_MODEL 2048
#define NHEAD   16
#define DHEAD   128

using f32x4   = __attribute__((ext_vector_type(4))) float;
using f32x16  = __attribute__((ext_vector_type(16))) float;
using bf16x8  = __attribute__((ext_vector_type(8))) __bf16;

__device__ __forceinline__ unsigned short f2bf(float f) {
  unsigned int u = __builtin_bit_cast(unsigned int, f);
  u += 0x7fffu + ((u >> 16) & 1u);          // RNE
  return (unsigned short)(u >> 16);
}
__device__ __forceinline__ int chunks_of(int qt) { return (4 * qt + 13) / 10; } // ceil((4qt+4)/10)

// async global->LDS, 16B per lane. LDS dest is wave-uniform base + lane*16.
__device__ __forceinline__ void gl_lds16(const unsigned short* g, char* l) {
  __builtin_amdgcn_global_load_lds(
      (const __attribute__((address_space(1))) unsigned int*)g,
      (__attribute__((address_space(3))) unsigned int*)l, 16, 0, 0);
}

// ---------- fp32 -> bf16 copy (x) ----------
__global__ void k_cvt(const float* __restrict__ in, unsigned short* __restrict__ out) {
  int i = (blockIdx.x * 256 + threadIdx.x) * 4;
  float4 v = *reinterpret_cast<const float4*>(in + i);
  ushort4 o; o.x = f2bf(v.x); o.y = f2bf(v.y); o.z = f2bf(v.z); o.w = f2bf(v.w);
  *reinterpret_cast<ushort4*>(out + i) = o;
}

// ---------- RoPE sin/cos tables ----------
__global__ void k_tab(const float* __restrict__ theta_p, float* __restrict__ sint,
                      float* __restrict__ cost) {
  int i = blockIdx.x * 256 + threadIdx.x;   // [0, 2048*64)
  int s = i >> 6, c = i & 63;
  float rate = theta_p[0] * (-(float)c / 64.0f);
  float sn, cs;
  sincosf((float)s * rate, &sn, &cs);
  sint[i] = sn; cost[i] = cs;
}

// ---------- transpose+convert: fp32 (B,R,C) -> bf16 (B,C,R) ----------
__global__ void k_tr(const float* __restrict__ in, unsigned short* __restrict__ out,
                     int R, int C) {
  __shared__ float t[32][33];
  int b = blockIdx.x, rt = blockIdx.y, ct = blockIdx.z;
  const float* ip = in + (size_t)b * R * C;
  unsigned short* op = out + (size_t)b * R * C;
  int tx = threadIdx.x & 31, ty = threadIdx.x >> 5;   // 32 x 8
  #pragma unroll
  for (int i = 0; i < 4; i++)
    t[ty + i * 8][tx] = ip[(size_t)(rt * 32 + ty + i * 8) * C + ct * 32 + tx];
  __syncthreads();
  #pragma unroll
  for (int i = 0; i < 4; i++)
    op[(size_t)(ct * 32 + ty + i * 8) * R + rt * 32 + tx] = f2bf(t[tx][ty + i * 8]);
}

// ---------- merged projection GEMM: C(2048 x 6144) = xb @ W^T, RoPE epilogue ----------
// 768 blocks (XCD-swizzled); 4 waves x (32 rows x 128 cols); 2-phase double-
// buffered gl_lds staging with counted vmcnt(8) (T3+T4): next tile's loads stay
// in flight across the barrier; load latency hides under current tile's MFMA.
__global__ __launch_bounds__(256) void k_proj2(
    const unsigned short* __restrict__ xb, const unsigned short* __restrict__ wT,
    const float* __restrict__ sint, const float* __restrict__ cost,
    unsigned short* __restrict__ rq, unsigned short* __restrict__ rk,
    unsigned short* __restrict__ vst) {
  __shared__ char lds[65536];               // buf0: A@0 B@16K | buf1: A@32K B@48K
  const int tid = threadIdx.x, l = tid & 63, w = tid >> 6;
  const int lr = l & 15, lk = l >> 4;
  const int orig = blockIdx.x;
  const int wg = (orig & 7) * 96 + (orig >> 3);   // XCD-contiguous remap (768%8==0)
  const int bx = wg & 15, by = wg >> 4;     // s-tile, n-tile
  const int s0 = bx * 128;
  const int h = by & 15, which = by >> 4;   // n-tile -> (head, q/k/v)
  const unsigned short* bbase = wT + (size_t)by * 128 * D_MODEL;

  f32x4 acc[2][8] = {};

  // stage K-tile t into buffer buf (8 gl_lds per wave; swizzled source, linear dest)
  auto stage = [&](int t, int buf) {
    const int kt = t * 64;
    char* dst = lds + buf * 32768;
    #pragma unroll
    for (int j = 0; j < 4; j++) {
      int ci = (j * 4 + w) * 64 + l;        // 0..1023
      int r = ci >> 3, c8 = ci & 7;
      int csrc = (c8 ^ (r & 7)) * 8;
      gl_lds16(xb + (size_t)(s0 + r) * D_MODEL + kt + csrc, dst + ci * 16);
      gl_lds16(bbase + (size_t)r * D_MODEL + kt + csrc, dst + 16384 + ci * 16);
    }
  };

  stage(0, 0);
  int cur = 0;
  const int nT = D_MODEL / 64;              // 32
  for (int t = 0; t < nT; t++) {
    if (t + 1 < nT) {
      stage(t + 1, cur ^ 1);
      asm volatile("s_waitcnt vmcnt(8)" ::: "memory");   // buf[cur]'s 8 done
    } else {
      asm volatile("s_waitcnt vmcnt(0)" ::: "memory");
    }
    __builtin_amdgcn_s_barrier();           // all waves' buf[cur] resident
    const char* base = lds + cur * 32768;
    #pragma unroll
    for (int kk = 0; kk < 2; kk++) {
      const int kb = kk * 64 + lk * 16;
      bf16x8 a[2], b[8];
      #pragma unroll
      for (int mf = 0; mf < 2; mf++) {
        int rr = w * 32 + mf * 16 + lr;
        a[mf] = *reinterpret_cast<const bf16x8*>(base + rr * 128 + (kb ^ ((rr & 7) << 4)));
      }
      #pragma unroll
      for (int nf = 0; nf < 8; nf++) {
        int rn = nf * 16 + lr;
        b[nf] = *reinterpret_cast<const bf16x8*>(base + 16384 + rn * 128 + (kb ^ ((rn & 7) << 4)));
      }
      #pragma unroll
      for (int mf = 0; mf < 2; mf++)
        #pragma unroll
        for (int nf = 0; nf < 8; nf++)
          acc[mf][nf] = __builtin_amdgcn_mfma_f32_16x16x32_bf16(a[mf], b[nf], acc[mf][nf], 0, 0, 0);
    }
    asm volatile("s_waitcnt lgkmcnt(0)" ::: "memory");   // reads of buf[cur] done
    __builtin_amdgcn_s_barrier();           // before next iter overwrites buf[cur]
    cur ^= 1;
  }

  const float xscale = 0.022097086912079608f;             // 1/sqrt(2048)
  const float qsc = xscale * 0.08838834764831845f;        // * 1/sqrt(128) folded
  if (which < 2) {
    const float sc_out = (which == 0) ? qsc : xscale;
    unsigned short* dst = (which == 0 ? rq : rk) + (size_t)h * S_LEN * DHEAD;
    #pragma unroll
    for (int mf = 0; mf < 2; mf++) {
      #pragma unroll
      for (int nf = 0; nf < 4; nf++) {
        int c1 = nf * 16 + lr;
        #pragma unroll
        for (int rg = 0; rg < 4; rg++) {
          int srow = s0 + w * 32 + mf * 16 + lk * 4 + rg;
          float sn = sint[srow * 64 + c1], cs = cost[srow * 64 + c1];
          float x1 = acc[mf][nf][rg] * sc_out;
          float x2 = acc[mf][nf + 4][rg] * sc_out;
          dst[(size_t)srow * DHEAD + c1]      = f2bf(cs * x1 - sn * x2);
          dst[(size_t)srow * DHEAD + c1 + 64] = f2bf(sn * x1 + cs * x2);
        }
      }
    }
  } else {                                      // v: store transposed vst[h][c][s]
    unsigned short* dst = vst + (size_t)h * DHEAD * S_LEN;
    #pragma unroll
    for (int mf = 0; mf < 2; mf++) {
      int rbase = s0 + w * 32 + mf * 16 + lk * 4;
      #pragma unroll
      for (int nf = 0; nf < 8; nf++) {
        int c = nf * 16 + lr;
        ushort4 ov;
        ov.x = f2bf(acc[mf][nf][0] * xscale); ov.y = f2bf(acc[mf][nf][1] * xscale);
        ov.z = f2bf(acc[mf][nf][2] * xscale); ov.w = f2bf(acc[mf][nf][3] * xscale);
        *reinterpret_cast<ushort4*>(dst + (size_t)c * S_LEN + rbase) = ov;
      }
    }
  }
}

// ---------- causal flash attention v5: uniform kv-chunks, padded-LDS K/V ----------
__global__ __launch_bounds__(256, 2) void k_attn5(
    const unsigned short* __restrict__ rq, const unsigned short* __restrict__ rk,
    const unsigned short* __restrict__ vst,
    unsigned short* __restrict__ opart, float2* __restrict__ mlbuf) {
  __shared__ uint4 ldsbuf[1184];            // 18944B: K @0 (8704), Vt @8704 (10240)
  char* lds = (char*)ldsbuf;
  const int tid = threadIdx.x, l = tid & 63, w = tid >> 6;
  const int hi = l >> 5, qcol = l & 31;
  const int b = blockIdx.x;
  const int h = b & 15;                     // head h -> XCD h&7 (K/V L2 locality)
  int u = b >> 4, qt = 0;
  while (u >= chunks_of(qt)) { u -= chunks_of(qt); qt++; }
  const int ntile = 4 * qt + 4;
  const int tbeg = u * 10;
  const int tend = (tbeg + 10 < ntile) ? tbeg + 10 : ntile;
  const int s0w = qt * 128 + w * 32;
  const int wlast = s0w + 31;
  const int dtile = s0w >> 5;               // diagonal tile index

  const unsigned short* rk_h  = rk  + (size_t)h * S_LEN * DHEAD;
  const unsigned short* vst_h = vst + (size_t)h * DHEAD * S_LEN;

  const unsigned short* qrow_p = rq + ((size_t)h * S_LEN + s0w + qcol) * DHEAD + hi * 8;
  bf16x8 qb[8];
  #pragma unroll
  for (int kk = 0; kk < 8; kk++)
    qb[kk] = *reinterpret_cast<const bf16x8*>(qrow_p + kk * 16);

  f32x16 O[4] = {};
  float mrow = -3.0e38f, lrow = 0.0f;

  uint4 kreg[2], vreg[2];
  {                                         // prefetch tile tbeg
    const int t0 = tbeg * 32;
    #pragma unroll
    for (int j = 0; j < 2; j++) {
      int ci = tid + j * 256;
      kreg[j] = *reinterpret_cast<const uint4*>(rk_h + (size_t)(t0 + (ci >> 4)) * DHEAD + (ci & 15) * 8);
      vreg[j] = *reinterpret_cast<const uint4*>(vst_h + (size_t)(ci >> 2) * S_LEN + t0 + (ci & 3) * 8);
    }
  }

  for (int t = tbeg; t < tend; t++) {
    __syncthreads();                        // prior tile's LDS reads done
    #pragma unroll
    for (int j = 0; j < 2; j++) {
      int ci = tid + j * 256;
      *reinterpret_cast<uint4*>(lds + (ci >> 4) * 272 + (ci & 15) * 16) = kreg[j];
      *reinterpret_cast<uint4*>(lds + 8704 + (ci >> 2) * 80 + (ci & 3) * 16) = vreg[j];
    }
    if (t + 1 < tend) {                     // T14: issue next tile's loads now
      const int t0n = (t + 1) * 32;
      #pragma unroll
      for (int j = 0; j < 2; j++) {
        int ci = tid + j * 256;
        kreg[j] = *reinterpret_cast<const uint4*>(rk_h + (size_t)(t0n + (ci >> 4)) * DHEAD + (ci & 15) * 8);
        vreg[j] = *reinterpret_cast<const uint4*>(vst_h + (size_t)(ci >> 2) * S_LEN + t0n + (ci & 3) * 8);
      }
    }
    __syncthreads();                        // staged tile visible
    const int tt0 = t * 32;
    if (tt0 <= wlast) {
      f32x16 sc = {};
      #pragma unroll
      for (int kk = 0; kk < 8; kk++) {
        bf16x8 ka = *reinterpret_cast<const bf16x8*>(lds + qcol * 272 + kk * 32 + hi * 16);
        sc = __builtin_amdgcn_mfma_f32_32x32x16_bf16(ka, qb[kk], sc, 0, 0, 0);
      }
      float p[16];
      #pragma unroll
      for (int r = 0; r < 16; r++) p[r] = sc[r];
      if (t == dtile) {                     // diagonal tile: causal mask
        #pragma unroll
        for (int r = 0; r < 16; r++)
          if (((r & 3) + 8 * (r >> 2) + 4 * hi) > qcol) p[r] = -1.0e9f;
      }
      float mx[8];
      #pragma unroll
      for (int i = 0; i < 8; i++) mx[i] = fmaxf(p[2 * i], p[2 * i + 1]);
      #pragma unroll
      for (int i = 0; i < 4; i++) mx[i] = fmaxf(mx[i], mx[i + 4]);
      mx[0] = fmaxf(mx[0], mx[2]); mx[1] = fmaxf(mx[1], mx[3]);
      float pmax = fmaxf(mx[0], mx[1]);
      pmax = fmaxf(pmax, __shfl_xor(pmax, 32, 64));
      if (__any(pmax > mrow + 8.0f)) {
        float mn = fmaxf(mrow, pmax);
        float sf = __expf(mrow - mn);
        lrow *= sf; mrow = mn;
        #pragma unroll
        for (int vc = 0; vc < 4; vc++)
          #pragma unroll
          for (int r = 0; r < 16; r++) O[vc][r] *= sf;
      }
      #pragma unroll
      for (int r = 0; r < 16; r++) p[r] = __expf(p[r] - mrow);
      float sm[8];
      #pragma unroll
      for (int i = 0; i < 8; i++) sm[i] = p[2 * i] + p[2 * i + 1];
      #pragma unroll
      for (int i = 0; i < 4; i++) sm[i] += sm[i + 4];
      float psum = (sm[0] + sm[1]) + (sm[2] + sm[3]);
      psum += __shfl_xor(psum, 32, 64);
      lrow += psum;
      unsigned int pk[2][4], sw[2][4];
      #pragma unroll
      for (int c = 0; c < 2; c++)
        #pragma unroll
        for (int k = 0; k < 4; k++) {
          unsigned int r_;
          asm("v_cvt_pk_bf16_f32 %0, %1, %2" : "=v"(r_)
              : "v"(p[8 * c + 2 * k]), "v"(p[8 * c + 2 * k + 1]));
          pk[c][k] = r_;
          sw[c][k] = (unsigned int)__shfl_xor((int)r_, 32, 64);
        }
      bf16x8 pb[2];
      #pragma unroll
      for (int c = 0; c < 2; c++) {
        union { unsigned int u4[4]; bf16x8 v; } bw;
        bw.u4[0] = hi ? sw[c][2] : pk[c][0];
        bw.u4[1] = hi ? sw[c][3] : pk[c][1];
        bw.u4[2] = hi ? pk[c][2] : sw[c][0];
        bw.u4[3] = hi ? pk[c][3] : sw[c][1];
        pb[c] = bw.v;
      }
      #pragma unroll
      for (int vc = 0; vc < 4; vc++) {
        const char* vrow = lds + 8704 + (vc * 32 + qcol) * 80 + hi * 16;
        bf16x8 va0 = *reinterpret_cast<const bf16x8*>(vrow);
        bf16x8 va1 = *reinterpret_cast<const bf16x8*>(vrow + 32);
        O[vc] = __builtin_amdgcn_mfma_f32_32x32x16_bf16(va0, pb[0], O[vc], 0, 0, 0);
        O[vc] = __builtin_amdgcn_mfma_f32_32x32x16_bf16(va1, pb[1], O[vc], 0, 0, 0);
      }
    }
  }
  float inv = lrow > 0.0f ? 1.0f / lrow : 0.0f;
  unsigned short* op = opart + ((size_t)b * 128 + w * 32 + qcol) * DHEAD;
  #pragma unroll
  for (int vc = 0; vc < 4; vc++)
    #pragma unroll
    for (int g = 0; g < 4; g++) {
      int v0 = vc * 32 + 8 * g + 4 * hi;
      ushort4 ov;
      ov.x = f2bf(O[vc][4 * g + 0] * inv); ov.y = f2bf(O[vc][4 * g + 1] * inv);
      ov.z = f2bf(O[vc][4 * g + 2] * inv); ov.w = f2bf(O[vc][4 * g + 3] * inv);
      *reinterpret_cast<ushort4*>(op + v0) = ov;
    }
  if (l < 32)
    mlbuf[(size_t)b * 128 + w * 32 + l] = make_float2(mrow, lrow);
}

// ---------- combine up to 7 chunk partials per (h, q-row) ----------
__global__ void k_comb2(const unsigned short* __restrict__ opart,
                        const float2* __restrict__ mlbuf,
                        unsigned short* __restrict__ z) {
  int g = blockIdx.x * 256 + threadIdx.x;     // 16h * 2048q * 16vg
  int vg = g & 15, q = (g >> 4) & 2047, h = g >> 15;
  int qt = q >> 7, r = q & 127;
  int base = 0;
  for (int j = 0; j < qt; j++) base += chunks_of(j);
  const int nc = chunks_of(qt);               // 1..7
  float m = -3.0e38f;
  float2 ml[7];
  #pragma unroll
  for (int cc = 0; cc < 7; cc++)
    if (cc < nc) {
      ml[cc] = mlbuf[(size_t)((base + cc) * 16 + h) * 128 + r];
      m = fmaxf(m, ml[cc].x);
    }
  float wts[7], wsum = 0.0f;
  #pragma unroll
  for (int cc = 0; cc < 7; cc++)
    if (cc < nc) {
      float wv = ml[cc].y > 0.0f ? ml[cc].y * __expf(ml[cc].x - m) : 0.0f;
      wts[cc] = wv; wsum += wv;
    }
  float wi = 1.0f / wsum;
  float acc[8] = {};
  #pragma unroll
  for (int cc = 0; cc < 7; cc++)
    if (cc < nc && wts[cc] > 0.0f) {
      float wv = wts[cc] * wi;
      bf16x8 v = *reinterpret_cast<const bf16x8*>(
          opart + ((size_t)((base + cc) * 16 + h) * 128 + r) * DHEAD + vg * 8);
      #pragma unroll
      for (int j = 0; j < 8; j++) acc[j] += wv * (float)v[j];
    }
  unsigned short* zp = z + (size_t)q * D_MODEL + h * DHEAD + vg * 8;
  ushort4 lo, hi4;
  lo.x = f2bf(acc[0]); lo.y = f2bf(acc[1]); lo.z = f2bf(acc[2]); lo.w = f2bf(acc[3]);
  hi4.x = f2bf(acc[4]); hi4.y = f2bf(acc[5]); hi4.z = f2bf(acc[6]); hi4.w = f2bf(acc[7]);
  *reinterpret_cast<ushort4*>(zp) = lo;
  *reinterpret_cast<ushort4*>(zp + 4) = hi4;
}

// ---------- output GEMM: out(S,D) = z(S,2048) @ obT^T, 2-phase dbuf counted vmcnt ----------
__global__ __launch_bounds__(256) void k_out2(
    const unsigned short* __restrict__ zb, const unsigned short* __restrict__ obT,
    float* __restrict__ out) {
  __shared__ char lds[65536];
  const int tid = threadIdx.x, l = tid & 63, w = tid >> 6;
  const int lr = l & 15, lk = l >> 4;
  const int orig = blockIdx.x;
  const int wg = (orig & 7) * 32 + (orig >> 3);   // 256%8==0, bijective
  const int bx = wg & 15, by = wg >> 4;
  const int s0 = bx * 128, n0 = by * 128;
  const int wm = w >> 1, wn = w & 1;
  f32x4 acc[4][4] = {};

  auto stage = [&](int t, int buf) {
    const int kt = t * 64;
    char* dst = lds + buf * 32768;
    #pragma unroll
    for (int j = 0; j < 4; j++) {
      int ci = (j * 4 + w) * 64 + l;
      int r = ci >> 3, c8 = ci & 7;
      int csrc = (c8 ^ (r & 7)) * 8;
      gl_lds16(zb + (size_t)(s0 + r) * D_MODEL + kt + csrc, dst + ci * 16);
      gl_lds16(obT + (size_t)(n0 + r) * D_MODEL + kt + csrc, dst + 16384 + ci * 16);
    }
  };

  stage(0, 0);
  int cur = 0;
  const int nT = D_MODEL / 64;
  for (int t = 0; t < nT; t++) {
    if (t + 1 < nT) {
      stage(t + 1, cur ^ 1);
      asm volatile("s_waitcnt vmcnt(8)" ::: "memory");
    } else {
      asm volatile("s_waitcnt vmcnt(0)" ::: "memory");
    }
    __builtin_amdgcn_s_barrier();
    const char* base = lds + cur * 32768;
    #pragma unroll
    for (int kk = 0; kk < 2; kk++) {
      const int kb = kk * 64 + lk * 16;
      bf16x8 a[4], b[4];
      #pragma unroll
      for (int mf = 0; mf < 4; mf++) {
        int rr = wm * 64 + mf * 16 + lr;
        a[mf] = *reinterpret_cast<const bf16x8*>(base + rr * 128 + (kb ^ ((rr & 7) << 4)));
      }
      #pragma unroll
      for (int nf = 0; nf < 4; nf++) {
        int rn = wn * 64 + nf * 16 + lr;
        b[nf] = *reinterpret_cast<const bf16x8*>(base + 16384 + rn * 128 + (kb ^ ((rn & 7) << 4)));
      }
      #pragma unroll
      for (int mf = 0; mf < 4; mf++)
        #pragma unroll
        for (int nf = 0; nf < 4; nf++)
          acc[mf][nf] = __builtin_amdgcn_mfma_f32_16x16x32_bf16(a[mf], b[nf], acc[mf][nf], 0, 0, 0);
    }
    asm volatile("s_waitcnt lgkmcnt(0)" ::: "memory");
    __builtin_amdgcn_s_barrier();
    cur ^= 1;
  }
  const float osc = 0.022097086912079608f;      // 1/sqrt(2048)
  #pragma unroll
  for (int mf = 0; mf < 4; mf++)
    #pragma unroll
    for (int nf = 0; nf < 4; nf++)
      #pragma unroll
      for (int rg = 0; rg < 4; rg++)
        out[(size_t)(s0 + wm * 64 + mf * 16 + lk * 4 + rg) * D_MODEL + n0 + wn * 64 + nf * 16 + lr]
            = acc[mf][nf][rg] * osc;
}

extern "C" void kernel_launch(void* const* d_in, const int* in_sizes, int n_in,
                              void* d_out, int out_size, void* d_ws, size_t ws_size,
                              hipStream_t stream) {
  const float* x = (const float*)d_in[0];
  const float* q = (const float*)d_in[1];
  const float* k = (const float*)d_in[2];
  const float* v = (const float*)d_in[3];
  const float* o = (const float*)d_in[4];
  const float* theta = (const float*)d_in[5];
  float* out = (float*)d_out;

  char* ws = (char*)d_ws;
  const size_t MB = 1u << 20;
  unsigned short* xb  = (unsigned short*)(ws + 0 * MB);
  unsigned short* qbT = (unsigned short*)(ws + 8 * MB);   // merged W^T[6144][2048] start
  unsigned short* kbT = (unsigned short*)(ws + 16 * MB);
  unsigned short* vbT = (unsigned short*)(ws + 24 * MB);
  unsigned short* obT = (unsigned short*)(ws + 32 * MB);
  unsigned short* rq  = (unsigned short*)(ws + 40 * MB);
  unsigned short* rk  = (unsigned short*)(ws + 48 * MB);
  unsigned short* vst = (unsigned short*)(ws + 56 * MB);
  float* sint = (float*)(ws + 64 * MB);
  float* cost = (float*)(ws + 64 * MB + 512 * 1024);
  unsigned short* opart = (unsigned short*)(ws + 0 * MB);   // 976*128*128*2B = 30.5MB
  float2* mlbuf         = (float2*)(ws + 31 * MB);          // 976*128*8B ~ 1MB
  unsigned short* zb    = (unsigned short*)(ws + 40 * MB);  // reuse rq (dead after attn)

  k_cvt<<<dim3(4096), dim3(256), 0, stream>>>(x, xb);
  k_tab<<<dim3(512), dim3(256), 0, stream>>>(theta, sint, cost);
  k_tr<<<dim3(16, 64, 4), dim3(256), 0, stream>>>(q, qbT, 2048, 128);
  k_tr<<<dim3(16, 64, 4), dim3(256), 0, stream>>>(k, kbT, 2048, 128);
  k_tr<<<dim3(16, 64, 4), dim3(256), 0, stream>>>(v, vbT, 2048, 128);
  k_tr<<<dim3(1, 64, 64), dim3(256), 0, stream>>>(o, obT, 2048, 2048);
  k_proj2<<<dim3(768), dim3(256), 0, stream>>>(xb, qbT, sint, cost, rq, rk, vst);
  k_attn5<<<dim3(976), dim3(256), 0, stream>>>(rq, rk, vst, opart, mlbuf);
  k_comb2<<<dim3(2048), dim3(256), 0, stream>>>(opart, mlbuf, zb);
  k_out2<<<dim3(256), dim3(256), 0, stream>>>(zb, obT, out);
}

// Round 8
// 192.082 us; speedup vs baseline: 1.7241x; 1.0437x over previous
//
#include <hip/hip_runtime.h>

// ShrdMHAttention on MI355X (gfx950).
// cvt/transpose -> merged proj GEMM (2-phase dbuf, counted vmcnt, gl_lds staging,
// RoPE epilogue) -> causal flash attention (dbuf padded-LDS K/V, ONE barrier per
// tile, swapped QK^T, in-register softmax, uniform kv-chunks, LDS-bounced
// coalesced O-write) -> combine -> output GEMM (dbuf counted vmcnt).
// Workspace: 0-30.5MB opart | 31MB mlbuf | 32MB obT | 40MB rq[->z] | 48MB rk |
// 56MB vst | 64MB tables.  Pre-proj: 0MB xb | 8..32MB merged W^T[6144][2048]

#define S_LEN   2048
#define D_MODEL 2048
#define NHEAD   16
#define DHEAD   128

using f32x4   = __attribute__((ext_vector_type(4))) float;
using f32x16  = __attribute__((ext_vector_type(16))) float;
using bf16x8  = __attribute__((ext_vector_type(8))) __bf16;

__device__ __forceinline__ unsigned short f2bf(float f) {
  unsigned int u = __builtin_bit_cast(unsigned int, f);
  u += 0x7fffu + ((u >> 16) & 1u);          // RNE
  return (unsigned short)(u >> 16);
}
__device__ __forceinline__ int chunks_of(int qt) { return (4 * qt + 13) / 10; } // ceil((4qt+4)/10)

// async global->LDS, 16B per lane. LDS dest is wave-uniform base + lane*16.
__device__ __forceinline__ void gl_lds16(const unsigned short* g, char* l) {
  __builtin_amdgcn_global_load_lds(
      (const __attribute__((address_space(1))) unsigned int*)g,
      (__attribute__((address_space(3))) unsigned int*)l, 16, 0, 0);
}

// ---------- fp32 -> bf16 copy (x) ----------
__global__ void k_cvt(const float* __restrict__ in, unsigned short* __restrict__ out) {
  int i = (blockIdx.x * 256 + threadIdx.x) * 4;
  float4 v = *reinterpret_cast<const float4*>(in + i);
  ushort4 o; o.x = f2bf(v.x); o.y = f2bf(v.y); o.z = f2bf(v.z); o.w = f2bf(v.w);
  *reinterpret_cast<ushort4*>(out + i) = o;
}

// ---------- RoPE sin/cos tables ----------
__global__ void k_tab(const float* __restrict__ theta_p, float* __restrict__ sint,
                      float* __restrict__ cost) {
  int i = blockIdx.x * 256 + threadIdx.x;   // [0, 2048*64)
  int s = i >> 6, c = i & 63;
  float rate = theta_p[0] * (-(float)c / 64.0f);
  float sn, cs;
  sincosf((float)s * rate, &sn, &cs);
  sint[i] = sn; cost[i] = cs;
}

// ---------- transpose+convert: fp32 (B,R,C) -> bf16 (B,C,R) ----------
__global__ void k_tr(const float* __restrict__ in, unsigned short* __restrict__ out,
                     int R, int C) {
  __shared__ float t[32][33];
  int b = blockIdx.x, rt = blockIdx.y, ct = blockIdx.z;
  const float* ip = in + (size_t)b * R * C;
  unsigned short* op = out + (size_t)b * R * C;
  int tx = threadIdx.x & 31, ty = threadIdx.x >> 5;   // 32 x 8
  #pragma unroll
  for (int i = 0; i < 4; i++)
    t[ty + i * 8][tx] = ip[(size_t)(rt * 32 + ty + i * 8) * C + ct * 32 + tx];
  __syncthreads();
  #pragma unroll
  for (int i = 0; i < 4; i++)
    op[(size_t)(ct * 32 + ty + i * 8) * R + rt * 32 + tx] = f2bf(t[tx][ty + i * 8]);
}

// ---------- merged projection GEMM: C(2048 x 6144) = xb @ W^T, RoPE epilogue ----------
__global__ __launch_bounds__(256) void k_proj2(
    const unsigned short* __restrict__ xb, const unsigned short* __restrict__ wT,
    const float* __restrict__ sint, const float* __restrict__ cost,
    unsigned short* __restrict__ rq, unsigned short* __restrict__ rk,
    unsigned short* __restrict__ vst) {
  __shared__ char lds[65536];               // buf0: A@0 B@16K | buf1: A@32K B@48K
  const int tid = threadIdx.x, l = tid & 63, w = tid >> 6;
  const int lr = l & 15, lk = l >> 4;
  const int orig = blockIdx.x;
  const int wg = (orig & 7) * 96 + (orig >> 3);   // XCD-contiguous remap (768%8==0)
  const int bx = wg & 15, by = wg >> 4;     // s-tile, n-tile
  const int s0 = bx * 128;
  const int h = by & 15, which = by >> 4;   // n-tile -> (head, q/k/v)
  const unsigned short* bbase = wT + (size_t)by * 128 * D_MODEL;

  f32x4 acc[2][8] = {};

  auto stage = [&](int t, int buf) {
    const int kt = t * 64;
    char* dst = lds + buf * 32768;
    #pragma unroll
    for (int j = 0; j < 4; j++) {
      int ci = (j * 4 + w) * 64 + l;        // 0..1023
      int r = ci >> 3, c8 = ci & 7;
      int csrc = (c8 ^ (r & 7)) * 8;
      gl_lds16(xb + (size_t)(s0 + r) * D_MODEL + kt + csrc, dst + ci * 16);
      gl_lds16(bbase + (size_t)r * D_MODEL + kt + csrc, dst + 16384 + ci * 16);
    }
  };

  stage(0, 0);
  int cur = 0;
  const int nT = D_MODEL / 64;              // 32
  for (int t = 0; t < nT; t++) {
    if (t + 1 < nT) {
      stage(t + 1, cur ^ 1);
      asm volatile("s_waitcnt vmcnt(8)" ::: "memory");   // buf[cur]'s 8 done
    } else {
      asm volatile("s_waitcnt vmcnt(0)" ::: "memory");
    }
    __builtin_amdgcn_s_barrier();           // all waves' buf[cur] resident
    const char* base = lds + cur * 32768;
    #pragma unroll
    for (int kk = 0; kk < 2; kk++) {
      const int kb = kk * 64 + lk * 16;
      bf16x8 a[2], b[8];
      #pragma unroll
      for (int mf = 0; mf < 2; mf++) {
        int rr = w * 32 + mf * 16 + lr;
        a[mf] = *reinterpret_cast<const bf16x8*>(base + rr * 128 + (kb ^ ((rr & 7) << 4)));
      }
      #pragma unroll
      for (int nf = 0; nf < 8; nf++) {
        int rn = nf * 16 + lr;
        b[nf] = *reinterpret_cast<const bf16x8*>(base + 16384 + rn * 128 + (kb ^ ((rn & 7) << 4)));
      }
      #pragma unroll
      for (int mf = 0; mf < 2; mf++)
        #pragma unroll
        for (int nf = 0; nf < 8; nf++)
          acc[mf][nf] = __builtin_amdgcn_mfma_f32_16x16x32_bf16(a[mf], b[nf], acc[mf][nf], 0, 0, 0);
    }
    asm volatile("s_waitcnt lgkmcnt(0)" ::: "memory");   // reads of buf[cur] done
    __builtin_amdgcn_s_barrier();           // before next iter overwrites buf[cur]
    cur ^= 1;
  }

  const float xscale = 0.022097086912079608f;             // 1/sqrt(2048)
  const float qsc = xscale * 0.08838834764831845f;        // * 1/sqrt(128) folded
  if (which < 2) {
    const float sc_out = (which == 0) ? qsc : xscale;
    unsigned short* dst = (which == 0 ? rq : rk) + (size_t)h * S_LEN * DHEAD;
    #pragma unroll
    for (int mf = 0; mf < 2; mf++) {
      #pragma unroll
      for (int nf = 0; nf < 4; nf++) {
        int c1 = nf * 16 + lr;
        #pragma unroll
        for (int rg = 0; rg < 4; rg++) {
          int srow = s0 + w * 32 + mf * 16 + lk * 4 + rg;
          float sn = sint[srow * 64 + c1], cs = cost[srow * 64 + c1];
          float x1 = acc[mf][nf][rg] * sc_out;
          float x2 = acc[mf][nf + 4][rg] * sc_out;
          dst[(size_t)srow * DHEAD + c1]      = f2bf(cs * x1 - sn * x2);
          dst[(size_t)srow * DHEAD + c1 + 64] = f2bf(sn * x1 + cs * x2);
        }
      }
    }
  } else {                                      // v: store transposed vst[h][c][s]
    unsigned short* dst = vst + (size_t)h * DHEAD * S_LEN;
    #pragma unroll
    for (int mf = 0; mf < 2; mf++) {
      int rbase = s0 + w * 32 + mf * 16 + lk * 4;
      #pragma unroll
      for (int nf = 0; nf < 8; nf++) {
        int c = nf * 16 + lr;
        ushort4 ov;
        ov.x = f2bf(acc[mf][nf][0] * xscale); ov.y = f2bf(acc[mf][nf][1] * xscale);
        ov.z = f2bf(acc[mf][nf][2] * xscale); ov.w = f2bf(acc[mf][nf][3] * xscale);
        *reinterpret_cast<ushort4*>(dst + (size_t)c * S_LEN + rbase) = ov;
      }
    }
  }
}

// ---------- causal flash attention v6: single-barrier dbuf, bounced O-write ----------
// 976 blocks = 16h x 61 units; 4 waves x 32 q-rows; KVBLK=32.
// LDS: buf p @ p*18944 { K rows @272B (8704) | Vt rows @80B (10240) };
// bounce region reuses 128 rows @272B (34816 <= 37888).
__global__ __launch_bounds__(256, 2) void k_attn6(
    const unsigned short* __restrict__ rq, const unsigned short* __restrict__ rk,
    const unsigned short* __restrict__ vst,
    unsigned short* __restrict__ opart, float2* __restrict__ mlbuf) {
  __shared__ uint4 ldsbuf[2368];            // 37888 B
  char* lds = (char*)ldsbuf;
  const int tid = threadIdx.x, l = tid & 63, w = tid >> 6;
  const int hi = l >> 5, qcol = l & 31;
  const int b = blockIdx.x;
  const int h = b & 15;                     // head h -> XCD h&7 (K/V L2 locality)
  int u = b >> 4, qt = 0;
  while (u >= chunks_of(qt)) { u -= chunks_of(qt); qt++; }
  const int ntile = 4 * qt + 4;
  const int tbeg = u * 10;
  const int tend = (tbeg + 10 < ntile) ? tbeg + 10 : ntile;
  const int s0w = qt * 128 + w * 32;
  const int wlast = s0w + 31;
  const int dtile = s0w >> 5;               // diagonal tile index

  const unsigned short* rk_h  = rk  + (size_t)h * S_LEN * DHEAD;
  const unsigned short* vst_h = vst + (size_t)h * DHEAD * S_LEN;

  const unsigned short* qrow_p = rq + ((size_t)h * S_LEN + s0w + qcol) * DHEAD + hi * 8;
  bf16x8 qb[8];
  #pragma unroll
  for (int kk = 0; kk < 8; kk++)
    qb[kk] = *reinterpret_cast<const bf16x8*>(qrow_p + kk * 16);

  f32x16 O[4] = {};
  float mrow = -3.0e38f, lrow = 0.0f;

  uint4 kreg[2], vreg[2];
  auto ld_regs = [&](int t) {               // issue tile t's global loads
    const int t0 = t * 32;
    #pragma unroll
    for (int j = 0; j < 2; j++) {
      int ci = tid + j * 256;
      kreg[j] = *reinterpret_cast<const uint4*>(rk_h + (size_t)(t0 + (ci >> 4)) * DHEAD + (ci & 15) * 8);
      vreg[j] = *reinterpret_cast<const uint4*>(vst_h + (size_t)(ci >> 2) * S_LEN + t0 + (ci & 3) * 8);
    }
  };
  auto wr_lds = [&](int p) {                // write staged regs into buffer p
    char* dst = lds + p * 18944;
    #pragma unroll
    for (int j = 0; j < 2; j++) {
      int ci = tid + j * 256;
      *reinterpret_cast<uint4*>(dst + (ci >> 4) * 272 + (ci & 15) * 16) = kreg[j];
      *reinterpret_cast<uint4*>(dst + 8704 + (ci >> 2) * 80 + (ci & 3) * 16) = vreg[j];
    }
  };

  // prologue: tile tbeg -> buf0; issue tbeg+1 loads
  ld_regs(tbeg);
  wr_lds(0);                                // compiler inserts vmcnt dep-wait
  if (tbeg + 1 < tend) ld_regs(tbeg + 1);
  asm volatile("s_waitcnt lgkmcnt(0)" ::: "memory");
  __builtin_amdgcn_s_barrier();

  int cur = 0;
  for (int t = tbeg; t < tend; t++) {
    const char* kb = lds + cur * 18944;
    const char* vb = kb + 8704;
    const int tt0 = t * 32;
    if (tt0 <= wlast) {
      // --- QK^T (verified math) ---
      f32x16 sc = {};
      #pragma unroll
      for (int kk = 0; kk < 8; kk++) {
        bf16x8 ka = *reinterpret_cast<const bf16x8*>(kb + qcol * 272 + kk * 32 + hi * 16);
        sc = __builtin_amdgcn_mfma_f32_32x32x16_bf16(ka, qb[kk], sc, 0, 0, 0);
      }
      float p[16];
      #pragma unroll
      for (int r = 0; r < 16; r++) p[r] = sc[r];
      if (t == dtile) {                     // diagonal tile: causal mask
        #pragma unroll
        for (int r = 0; r < 16; r++)
          if (((r & 3) + 8 * (r >> 2) + 4 * hi) > qcol) p[r] = -1.0e9f;
      }
      float mx[8];
      #pragma unroll
      for (int i = 0; i < 8; i++) mx[i] = fmaxf(p[2 * i], p[2 * i + 1]);
      #pragma unroll
      for (int i = 0; i < 4; i++) mx[i] = fmaxf(mx[i], mx[i + 4]);
      mx[0] = fmaxf(mx[0], mx[2]); mx[1] = fmaxf(mx[1], mx[3]);
      float pmax = fmaxf(mx[0], mx[1]);
      pmax = fmaxf(pmax, __shfl_xor(pmax, 32, 64));
      if (__any(pmax > mrow + 8.0f)) {
        float mn = fmaxf(mrow, pmax);
        float sf = __expf(mrow - mn);
        lrow *= sf; mrow = mn;
        #pragma unroll
        for (int vc = 0; vc < 4; vc++)
          #pragma unroll
          for (int r = 0; r < 16; r++) O[vc][r] *= sf;
      }
      #pragma unroll
      for (int r = 0; r < 16; r++) p[r] = __expf(p[r] - mrow);
      float sm[8];
      #pragma unroll
      for (int i = 0; i < 8; i++) sm[i] = p[2 * i] + p[2 * i + 1];
      #pragma unroll
      for (int i = 0; i < 4; i++) sm[i] += sm[i + 4];
      float psum = (sm[0] + sm[1]) + (sm[2] + sm[3]);
      psum += __shfl_xor(psum, 32, 64);
      lrow += psum;
      unsigned int pk[2][4], sw[2][4];
      #pragma unroll
      for (int c = 0; c < 2; c++)
        #pragma unroll
        for (int k = 0; k < 4; k++) {
          unsigned int r_;
          asm("v_cvt_pk_bf16_f32 %0, %1, %2" : "=v"(r_)
              : "v"(p[8 * c + 2 * k]), "v"(p[8 * c + 2 * k + 1]));
          pk[c][k] = r_;
          sw[c][k] = (unsigned int)__shfl_xor((int)r_, 32, 64);
        }
      bf16x8 pb[2];
      #pragma unroll
      for (int c = 0; c < 2; c++) {
        union { unsigned int u4[4]; bf16x8 v; } bw;
        bw.u4[0] = hi ? sw[c][2] : pk[c][0];
        bw.u4[1] = hi ? sw[c][3] : pk[c][1];
        bw.u4[2] = hi ? pk[c][2] : sw[c][0];
        bw.u4[3] = hi ? pk[c][3] : sw[c][1];
        pb[c] = bw.v;
      }
      #pragma unroll
      for (int vc = 0; vc < 4; vc++) {
        const char* vrow = vb + (vc * 32 + qcol) * 80 + hi * 16;
        bf16x8 va0 = *reinterpret_cast<const bf16x8*>(vrow);
        bf16x8 va1 = *reinterpret_cast<const bf16x8*>(vrow + 32);
        O[vc] = __builtin_amdgcn_mfma_f32_32x32x16_bf16(va0, pb[0], O[vc], 0, 0, 0);
        O[vc] = __builtin_amdgcn_mfma_f32_32x32x16_bf16(va1, pb[1], O[vc], 0, 0, 0);
      }
    }
    // stage tile t+1 into other buffer; issue t+2 loads (stay in flight)
    if (t + 1 < tend) {
      wr_lds(cur ^ 1);                      // compiler waits t+1 reg deps
      if (t + 2 < tend) ld_regs(t + 2);
    }
    asm volatile("s_waitcnt lgkmcnt(0)" ::: "memory");   // ds reads+writes done
    __builtin_amdgcn_s_barrier();
    cur ^= 1;
  }

  // --- bounce O through LDS for coalesced full-line global writes ---
  __syncthreads();                          // everyone done with K/V buffers
  float inv = lrow > 0.0f ? 1.0f / lrow : 0.0f;
  #pragma unroll
  for (int vc = 0; vc < 4; vc++)
    #pragma unroll
    for (int g = 0; g < 4; g++) {
      int v0 = vc * 32 + 8 * g + 4 * hi;
      ushort4 ov;
      ov.x = f2bf(O[vc][4 * g + 0] * inv); ov.y = f2bf(O[vc][4 * g + 1] * inv);
      ov.z = f2bf(O[vc][4 * g + 2] * inv); ov.w = f2bf(O[vc][4 * g + 3] * inv);
      *reinterpret_cast<ushort4*>(lds + (w * 32 + qcol) * 272 + v0 * 2) = ov;
    }
  __syncthreads();
  #pragma unroll
  for (int j = 0; j < 8; j++) {             // each instr: wave covers 1KB contiguous
    int row = w * 32 + j * 4 + (l >> 4);
    uint4 vv = *reinterpret_cast<const uint4*>(lds + row * 272 + (l & 15) * 16);
    *reinterpret_cast<uint4*>(opart + ((size_t)b * 128 + row) * DHEAD + (l & 15) * 8) = vv;
  }
  if (l < 32)
    mlbuf[(size_t)b * 128 + w * 32 + l] = make_float2(mrow, lrow);
}

// ---------- combine up to 7 chunk partials per (h, q-row) ----------
__global__ void k_comb2(const unsigned short* __restrict__ opart,
                        const float2* __restrict__ mlbuf,
                        unsigned short* __restrict__ z) {
  int g = blockIdx.x * 256 + threadIdx.x;     // 16h * 2048q * 16vg
  int vg = g & 15, q = (g >> 4) & 2047, h = g >> 15;
  int qt = q >> 7, r = q & 127;
  int base = 0;
  for (int j = 0; j < qt; j++) base += chunks_of(j);
  const int nc = chunks_of(qt);               // 1..7
  float m = -3.0e38f;
  float2 ml[7];
  #pragma unroll
  for (int cc = 0; cc < 7; cc++)
    if (cc < nc) {
      ml[cc] = mlbuf[(size_t)((base + cc) * 16 + h) * 128 + r];
      m = fmaxf(m, ml[cc].x);
    }
  float wts[7], wsum = 0.0f;
  #pragma unroll
  for (int cc = 0; cc < 7; cc++)
    if (cc < nc) {
      float wv = ml[cc].y > 0.0f ? ml[cc].y * __expf(ml[cc].x - m) : 0.0f;
      wts[cc] = wv; wsum += wv;
    }
  float wi = 1.0f / wsum;
  float acc[8] = {};
  #pragma unroll
  for (int cc = 0; cc < 7; cc++)
    if (cc < nc && wts[cc] > 0.0f) {
      float wv = wts[cc] * wi;
      bf16x8 v = *reinterpret_cast<const bf16x8*>(
          opart + ((size_t)((base + cc) * 16 + h) * 128 + r) * DHEAD + vg * 8);
      #pragma unroll
      for (int j = 0; j < 8; j++) acc[j] += wv * (float)v[j];
    }
  unsigned short* zp = z + (size_t)q * D_MODEL + h * DHEAD + vg * 8;
  ushort4 lo, hi4;
  lo.x = f2bf(acc[0]); lo.y = f2bf(acc[1]); lo.z = f2bf(acc[2]); lo.w = f2bf(acc[3]);
  hi4.x = f2bf(acc[4]); hi4.y = f2bf(acc[5]); hi4.z = f2bf(acc[6]); hi4.w = f2bf(acc[7]);
  *reinterpret_cast<ushort4*>(zp) = lo;
  *reinterpret_cast<ushort4*>(zp + 4) = hi4;
}

// ---------- output GEMM: out(S,D) = z(S,2048) @ obT^T, 2-phase dbuf counted vmcnt ----------
__global__ __launch_bounds__(256) void k_out2(
    const unsigned short* __restrict__ zb, const unsigned short* __restrict__ obT,
    float* __restrict__ out) {
  __shared__ char lds[65536];
  const int tid = threadIdx.x, l = tid & 63, w = tid >> 6;
  const int lr = l & 15, lk = l >> 4;
  const int orig = blockIdx.x;
  const int wg = (orig & 7) * 32 + (orig >> 3);   // 256%8==0, bijective
  const int bx = wg & 15, by = wg >> 4;
  const int s0 = bx * 128, n0 = by * 128;
  const int wm = w >> 1, wn = w & 1;
  f32x4 acc[4][4] = {};

  auto stage = [&](int t, int buf) {
    const int kt = t * 64;
    char* dst = lds + buf * 32768;
    #pragma unroll
    for (int j = 0; j < 4; j++) {
      int ci = (j * 4 + w) * 64 + l;
      int r = ci >> 3, c8 = ci & 7;
      int csrc = (c8 ^ (r & 7)) * 8;
      gl_lds16(zb + (size_t)(s0 + r) * D_MODEL + kt + csrc, dst + ci * 16);
      gl_lds16(obT + (size_t)(n0 + r) * D_MODEL + kt + csrc, dst + 16384 + ci * 16);
    }
  };

  stage(0, 0);
  int cur = 0;
  const int nT = D_MODEL / 64;
  for (int t = 0; t < nT; t++) {
    if (t + 1 < nT) {
      stage(t + 1, cur ^ 1);
      asm volatile("s_waitcnt vmcnt(8)" ::: "memory");
    } else {
      asm volatile("s_waitcnt vmcnt(0)" ::: "memory");
    }
    __builtin_amdgcn_s_barrier();
    const char* base = lds + cur * 32768;
    #pragma unroll
    for (int kk = 0; kk < 2; kk++) {
      const int kb = kk * 64 + lk * 16;
      bf16x8 a[4], b[4];
      #pragma unroll
      for (int mf = 0; mf < 4; mf++) {
        int rr = wm * 64 + mf * 16 + lr;
        a[mf] = *reinterpret_cast<const bf16x8*>(base + rr * 128 + (kb ^ ((rr & 7) << 4)));
      }
      #pragma unroll
      for (int nf = 0; nf < 4; nf++) {
        int rn = wn * 64 + nf * 16 + lr;
        b[nf] = *reinterpret_cast<const bf16x8*>(base + 16384 + rn * 128 + (kb ^ ((rn & 7) << 4)));
      }
      #pragma unroll
      for (int mf = 0; mf < 4; mf++)
        #pragma unroll
        for (int nf = 0; nf < 4; nf++)
          acc[mf][nf] = __builtin_amdgcn_mfma_f32_16x16x32_bf16(a[mf], b[nf], acc[mf][nf], 0, 0, 0);
    }
    asm volatile("s_waitcnt lgkmcnt(0)" ::: "memory");
    __builtin_amdgcn_s_barrier();
    cur ^= 1;
  }
  const float osc = 0.022097086912079608f;      // 1/sqrt(2048)
  #pragma unroll
  for (int mf = 0; mf < 4; mf++)
    #pragma unroll
    for (int nf = 0; nf < 4; nf++)
      #pragma unroll
      for (int rg = 0; rg < 4; rg++)
        out[(size_t)(s0 + wm * 64 + mf * 16 + lk * 4 + rg) * D_MODEL + n0 + wn * 64 + nf * 16 + lr]
            = acc[mf][nf][rg] * osc;
}

extern "C" void kernel_launch(void* const* d_in, const int* in_sizes, int n_in,
                              void* d_out, int out_size, void* d_ws, size_t ws_size,
                              hipStream_t stream) {
  const float* x = (const float*)d_in[0];
  const float* q = (const float*)d_in[1];
  const float* k = (const float*)d_in[2];
  const float* v = (const float*)d_in[3];
  const float* o = (const float*)d_in[4];
  const float* theta = (const float*)d_in[5];
  float* out = (float*)d_out;

  char* ws = (char*)d_ws;
  const size_t MB = 1u << 20;
  unsigned short* xb  = (unsigned short*)(ws + 0 * MB);
  unsigned short* qbT = (unsigned short*)(ws + 8 * MB);   // merged W^T[6144][2048] start
  unsigned short* kbT = (unsigned short*)(ws + 16 * MB);
  unsigned short* vbT = (unsigned short*)(ws + 24 * MB);
  unsigned short* obT = (unsigned short*)(ws + 32 * MB);
  unsigned short* rq  = (unsigned short*)(ws + 40 * MB);
  unsigned short* rk  = (unsigned short*)(ws + 48 * MB);
  unsigned short* vst = (unsigned short*)(ws + 56 * MB);
  float* sint = (float*)(ws + 64 * MB);
  float* cost = (float*)(ws + 64 * MB + 512 * 1024);
  unsigned short* opart = (unsigned short*)(ws + 0 * MB);   // 976*128*128*2B = 30.5MB
  float2* mlbuf         = (float2*)(ws + 31 * MB);          // 976*128*8B ~ 1MB
  unsigned short* zb    = (unsigned short*)(ws + 40 * MB);  // reuse rq (dead after attn)

  k_cvt<<<dim3(4096), dim3(256), 0, stream>>>(x, xb);
  k_tab<<<dim3(512), dim3(256), 0, stream>>>(theta, sint, cost);
  k_tr<<<dim3(16, 64, 4), dim3(256), 0, stream>>>(q, qbT, 2048, 128);
  k_tr<<<dim3(16, 64, 4), dim3(256), 0, stream>>>(k, kbT, 2048, 128);
  k_tr<<<dim3(16, 64, 4), dim3(256), 0, stream>>>(v, vbT, 2048, 128);
  k_tr<<<dim3(1, 64, 64), dim3(256), 0, stream>>>(o, obT, 2048, 2048);
  k_proj2<<<dim3(768), dim3(256), 0, stream>>>(xb, qbT, sint, cost, rq, rk, vst);
  k_attn6<<<dim3(976), dim3(256), 0, stream>>>(rq, rk, vst, opart, mlbuf);
  k_comb2<<<dim3(2048), dim3(256), 0, stream>>>(opart, mlbuf, zb);
  k_out2<<<dim3(256), dim3(256), 0, stream>>>(zb, obT, out);
}

// Round 9
// 180.449 us; speedup vs baseline: 1.8352x; 1.0645x over previous
//
#include <hip/hip_runtime.h>

// ShrdMHAttention on MI355X (gfx950).
// k_prep (cvt+tables+transposes, one launch) -> merged proj GEMM (BK=32, 2-phase
// dbuf, counted vmcnt(4), gl_lds staging, RoPE epilogue) -> causal flash attention
// (dbuf padded-LDS K/V, one barrier/tile, swapped QK^T, in-register softmax,
// uniform kv-chunks, LDS-bounced O-write) -> combine -> output GEMM (BM=64,
// grid 512, BK=64 dbuf counted vmcnt(6)).
// Workspace: 0-30.5MB opart | 31MB mlbuf | 32MB obT | 40MB rq[->z] | 48MB rk |
// 56MB vst | 64MB tables.  Pre-proj: 0MB xb | 8..32MB merged W^T[6144][2048]

#define S_LEN   2048
#define D_MODEL 2048
#define NHEAD   16
#define DHEAD   128

using f32x4   = __attribute__((ext_vector_type(4))) float;
using f32x16  = __attribute__((ext_vector_type(16))) float;
using bf16x8  = __attribute__((ext_vector_type(8))) __bf16;

__device__ __forceinline__ unsigned short f2bf(float f) {
  unsigned int u = __builtin_bit_cast(unsigned int, f);
  u += 0x7fffu + ((u >> 16) & 1u);          // RNE
  return (unsigned short)(u >> 16);
}
__device__ __forceinline__ int chunks_of(int qt) { return (4 * qt + 13) / 10; } // ceil((4qt+4)/10)

// async global->LDS, 16B per lane. LDS dest is wave-uniform base + lane*16.
__device__ __forceinline__ void gl_lds16(const unsigned short* g, char* l) {
  __builtin_amdgcn_global_load_lds(
      (const __attribute__((address_space(1))) unsigned int*)g,
      (__attribute__((address_space(3))) unsigned int*)l, 16, 0, 0);
}

// ---------- merged prep: bf16-cvt(x) | rope tables | transpose q,k,v,o ----------
// grid 20992 = 4096 cvt | 512 tab | 4x4096 transpose
__global__ __launch_bounds__(256) void k_prep(
    const float* __restrict__ x, const float* __restrict__ q,
    const float* __restrict__ k, const float* __restrict__ v,
    const float* __restrict__ o, const float* __restrict__ theta_p,
    unsigned short* __restrict__ xb, unsigned short* __restrict__ wT,
    unsigned short* __restrict__ obT, float* __restrict__ sint,
    float* __restrict__ cost) {
  __shared__ float t[32][33];
  const int bid = blockIdx.x, tid = threadIdx.x;
  if (bid < 4096) {                          // x -> bf16
    int i = (bid * 256 + tid) * 4;
    float4 vv = *reinterpret_cast<const float4*>(x + i);
    ushort4 ov; ov.x = f2bf(vv.x); ov.y = f2bf(vv.y); ov.z = f2bf(vv.z); ov.w = f2bf(vv.w);
    *reinterpret_cast<ushort4*>(xb + i) = ov;
  } else if (bid < 4608) {                   // rope tables
    int i = (bid - 4096) * 256 + tid;
    int s = i >> 6, c = i & 63;
    float rate = theta_p[0] * (-(float)c / 64.0f);
    float sn, cs;
    sincosf((float)s * rate, &sn, &cs);
    sint[i] = sn; cost[i] = cs;
  } else {                                   // transpose+cvt: (B,R,C) -> (B,C,R)
    int ti = bid - 4608;
    int which = ti >> 12, i = ti & 4095;
    const float* ip; unsigned short* op; int C, b, rt, ct;
    const int R = 2048;
    if (which < 3) {
      C = 128; b = i >> 8; rt = (i >> 2) & 63; ct = i & 3;
      const float* src = which == 0 ? q : (which == 1 ? k : v);
      ip = src + (size_t)b * R * C;
      op = wT + (size_t)which * 4194304 + (size_t)b * R * C;
    } else {
      C = 2048; rt = i >> 6; ct = i & 63;
      ip = o; op = obT;
    }
    int tx = tid & 31, ty = tid >> 5;        // 32 x 8
    #pragma unroll
    for (int j = 0; j < 4; j++)
      t[ty + j * 8][tx] = ip[(size_t)(rt * 32 + ty + j * 8) * C + ct * 32 + tx];
    __syncthreads();
    #pragma unroll
    for (int j = 0; j < 4; j++)
      op[(size_t)(ct * 32 + ty + j * 8) * R + rt * 32 + tx] = f2bf(t[tx][ty + j * 8]);
  }
}

// ---------- merged projection GEMM: C(2048 x 6144) = xb @ W^T, RoPE epilogue ----------
// 768 blocks (XCD-swizzled); 4 waves x (32 rows x 128 cols); BK=32, 2-phase dbuf
// gl_lds staging, counted vmcnt(4). LDS 32KB -> 3 blocks/CU (grid-capped).
// 64B rows: swizzle chunk = lk ^ ((r>>1)&3)  (2-way bank profile, free).
__global__ __launch_bounds__(256) void k_proj2(
    const unsigned short* __restrict__ xb, const unsigned short* __restrict__ wT,
    const float* __restrict__ sint, const float* __restrict__ cost,
    unsigned short* __restrict__ rq, unsigned short* __restrict__ rk,
    unsigned short* __restrict__ vst) {
  __shared__ char lds[32768];               // buf p @ p*16384: A[128][64B] | B @+8K
  const int tid = threadIdx.x, l = tid & 63, w = tid >> 6;
  const int lr = l & 15, lk = l >> 4;
  const int orig = blockIdx.x;
  const int wg = (orig & 7) * 96 + (orig >> 3);   // XCD-contiguous remap (768%8==0)
  const int bx = wg & 15, by = wg >> 4;     // s-tile, n-tile
  const int s0 = bx * 128;
  const int h = by & 15, which = by >> 4;   // n-tile -> (head, q/k/v)
  const unsigned short* bbase = wT + (size_t)by * 128 * D_MODEL;

  f32x4 acc[2][8] = {};

  auto stage = [&](int t, int buf) {        // 4 gl_lds/thread (2 A + 2 B)
    const int kt = t * 32;
    char* dst = lds + buf * 16384;
    #pragma unroll
    for (int j = 0; j < 2; j++) {
      int ci = tid + j * 256;               // 0..511 = (row, chunk4)
      int r = ci >> 2, c4 = ci & 3;
      int csrc = (c4 ^ ((r >> 1) & 3)) * 8;
      gl_lds16(xb + (size_t)(s0 + r) * D_MODEL + kt + csrc, dst + ci * 16);
      gl_lds16(bbase + (size_t)r * D_MODEL + kt + csrc, dst + 8192 + ci * 16);
    }
  };

  stage(0, 0);
  int cur = 0;
  const int nT = D_MODEL / 32;              // 64
  for (int t = 0; t < nT; t++) {
    if (t + 1 < nT) {
      stage(t + 1, cur ^ 1);
      asm volatile("s_waitcnt vmcnt(4)" ::: "memory");   // buf[cur]'s 4 done
    } else {
      asm volatile("s_waitcnt vmcnt(0)" ::: "memory");
    }
    __builtin_amdgcn_s_barrier();           // all waves' buf[cur] resident
    const char* base = lds + cur * 16384;
    bf16x8 a[2], b[8];
    #pragma unroll
    for (int mf = 0; mf < 2; mf++) {
      int rr = w * 32 + mf * 16 + lr;
      a[mf] = *reinterpret_cast<const bf16x8*>(base + rr * 64 + ((lk ^ ((rr >> 1) & 3)) * 16));
    }
    #pragma unroll
    for (int nf = 0; nf < 8; nf++) {
      int rn = nf * 16 + lr;
      b[nf] = *reinterpret_cast<const bf16x8*>(base + 8192 + rn * 64 + ((lk ^ ((rn >> 1) & 3)) * 16));
    }
    #pragma unroll
    for (int mf = 0; mf < 2; mf++)
      #pragma unroll
      for (int nf = 0; nf < 8; nf++)
        acc[mf][nf] = __builtin_amdgcn_mfma_f32_16x16x32_bf16(a[mf], b[nf], acc[mf][nf], 0, 0, 0);
    asm volatile("s_waitcnt lgkmcnt(0)" ::: "memory");   // reads of buf[cur] done
    __builtin_amdgcn_s_barrier();           // before next iter overwrites buf[cur]
    cur ^= 1;
  }

  const float xscale = 0.022097086912079608f;             // 1/sqrt(2048)
  const float qsc = xscale * 0.08838834764831845f;        // * 1/sqrt(128) folded
  if (which < 2) {
    const float sc_out = (which == 0) ? qsc : xscale;
    unsigned short* dst = (which == 0 ? rq : rk) + (size_t)h * S_LEN * DHEAD;
    #pragma unroll
    for (int mf = 0; mf < 2; mf++) {
      #pragma unroll
      for (int nf = 0; nf < 4; nf++) {
        int c1 = nf * 16 + lr;
        #pragma unroll
        for (int rg = 0; rg < 4; rg++) {
          int srow = s0 + w * 32 + mf * 16 + lk * 4 + rg;
          float sn = sint[srow * 64 + c1], cs = cost[srow * 64 + c1];
          float x1 = acc[mf][nf][rg] * sc_out;
          float x2 = acc[mf][nf + 4][rg] * sc_out;
          dst[(size_t)srow * DHEAD + c1]      = f2bf(cs * x1 - sn * x2);
          dst[(size_t)srow * DHEAD + c1 + 64] = f2bf(sn * x1 + cs * x2);
        }
      }
    }
  } else {                                      // v: store transposed vst[h][c][s]
    unsigned short* dst = vst + (size_t)h * DHEAD * S_LEN;
    #pragma unroll
    for (int mf = 0; mf < 2; mf++) {
      int rbase = s0 + w * 32 + mf * 16 + lk * 4;
      #pragma unroll
      for (int nf = 0; nf < 8; nf++) {
        int c = nf * 16 + lr;
        ushort4 ov;
        ov.x = f2bf(acc[mf][nf][0] * xscale); ov.y = f2bf(acc[mf][nf][1] * xscale);
        ov.z = f2bf(acc[mf][nf][2] * xscale); ov.w = f2bf(acc[mf][nf][3] * xscale);
        *reinterpret_cast<ushort4*>(dst + (size_t)c * S_LEN + rbase) = ov;
      }
    }
  }
}

// ---------- causal flash attention v6: single-barrier dbuf, bounced O-write ----------
__global__ __launch_bounds__(256, 2) void k_attn6(
    const unsigned short* __restrict__ rq, const unsigned short* __restrict__ rk,
    const unsigned short* __restrict__ vst,
    unsigned short* __restrict__ opart, float2* __restrict__ mlbuf) {
  __shared__ uint4 ldsbuf[2368];            // 37888 B
  char* lds = (char*)ldsbuf;
  const int tid = threadIdx.x, l = tid & 63, w = tid >> 6;
  const int hi = l >> 5, qcol = l & 31;
  const int b = blockIdx.x;
  const int h = b & 15;                     // head h -> XCD h&7 (K/V L2 locality)
  int u = b >> 4, qt = 0;
  while (u >= chunks_of(qt)) { u -= chunks_of(qt); qt++; }
  const int ntile = 4 * qt + 4;
  const int tbeg = u * 10;
  const int tend = (tbeg + 10 < ntile) ? tbeg + 10 : ntile;
  const int s0w = qt * 128 + w * 32;
  const int wlast = s0w + 31;
  const int dtile = s0w >> 5;               // diagonal tile index

  const unsigned short* rk_h  = rk  + (size_t)h * S_LEN * DHEAD;
  const unsigned short* vst_h = vst + (size_t)h * DHEAD * S_LEN;

  const unsigned short* qrow_p = rq + ((size_t)h * S_LEN + s0w + qcol) * DHEAD + hi * 8;
  bf16x8 qb[8];
  #pragma unroll
  for (int kk = 0; kk < 8; kk++)
    qb[kk] = *reinterpret_cast<const bf16x8*>(qrow_p + kk * 16);

  f32x16 O[4] = {};
  float mrow = -3.0e38f, lrow = 0.0f;

  uint4 kreg[2], vreg[2];
  auto ld_regs = [&](int t) {               // issue tile t's global loads
    const int t0 = t * 32;
    #pragma unroll
    for (int j = 0; j < 2; j++) {
      int ci = tid + j * 256;
      kreg[j] = *reinterpret_cast<const uint4*>(rk_h + (size_t)(t0 + (ci >> 4)) * DHEAD + (ci & 15) * 8);
      vreg[j] = *reinterpret_cast<const uint4*>(vst_h + (size_t)(ci >> 2) * S_LEN + t0 + (ci & 3) * 8);
    }
  };
  auto wr_lds = [&](int p) {                // write staged regs into buffer p
    char* dst = lds + p * 18944;
    #pragma unroll
    for (int j = 0; j < 2; j++) {
      int ci = tid + j * 256;
      *reinterpret_cast<uint4*>(dst + (ci >> 4) * 272 + (ci & 15) * 16) = kreg[j];
      *reinterpret_cast<uint4*>(dst + 8704 + (ci >> 2) * 80 + (ci & 3) * 16) = vreg[j];
    }
  };

  ld_regs(tbeg);
  wr_lds(0);
  if (tbeg + 1 < tend) ld_regs(tbeg + 1);
  asm volatile("s_waitcnt lgkmcnt(0)" ::: "memory");
  __builtin_amdgcn_s_barrier();

  int cur = 0;
  for (int t = tbeg; t < tend; t++) {
    const char* kb = lds + cur * 18944;
    const char* vb = kb + 8704;
    const int tt0 = t * 32;
    if (tt0 <= wlast) {
      f32x16 sc = {};
      #pragma unroll
      for (int kk = 0; kk < 8; kk++) {
        bf16x8 ka = *reinterpret_cast<const bf16x8*>(kb + qcol * 272 + kk * 32 + hi * 16);
        sc = __builtin_amdgcn_mfma_f32_32x32x16_bf16(ka, qb[kk], sc, 0, 0, 0);
      }
      float p[16];
      #pragma unroll
      for (int r = 0; r < 16; r++) p[r] = sc[r];
      if (t == dtile) {                     // diagonal tile: causal mask
        #pragma unroll
        for (int r = 0; r < 16; r++)
          if (((r & 3) + 8 * (r >> 2) + 4 * hi) > qcol) p[r] = -1.0e9f;
      }
      float mx[8];
      #pragma unroll
      for (int i = 0; i < 8; i++) mx[i] = fmaxf(p[2 * i], p[2 * i + 1]);
      #pragma unroll
      for (int i = 0; i < 4; i++) mx[i] = fmaxf(mx[i], mx[i + 4]);
      mx[0] = fmaxf(mx[0], mx[2]); mx[1] = fmaxf(mx[1], mx[3]);
      float pmax = fmaxf(mx[0], mx[1]);
      pmax = fmaxf(pmax, __shfl_xor(pmax, 32, 64));
      if (__any(pmax > mrow + 8.0f)) {
        float mn = fmaxf(mrow, pmax);
        float sf = __expf(mrow - mn);
        lrow *= sf; mrow = mn;
        #pragma unroll
        for (int vc = 0; vc < 4; vc++)
          #pragma unroll
          for (int r = 0; r < 16; r++) O[vc][r] *= sf;
      }
      #pragma unroll
      for (int r = 0; r < 16; r++) p[r] = __expf(p[r] - mrow);
      float sm[8];
      #pragma unroll
      for (int i = 0; i < 8; i++) sm[i] = p[2 * i] + p[2 * i + 1];
      #pragma unroll
      for (int i = 0; i < 4; i++) sm[i] += sm[i + 4];
      float psum = (sm[0] + sm[1]) + (sm[2] + sm[3]);
      psum += __shfl_xor(psum, 32, 64);
      lrow += psum;
      unsigned int pk[2][4], sw[2][4];
      #pragma unroll
      for (int c = 0; c < 2; c++)
        #pragma unroll
        for (int k = 0; k < 4; k++) {
          unsigned int r_;
          asm("v_cvt_pk_bf16_f32 %0, %1, %2" : "=v"(r_)
              : "v"(p[8 * c + 2 * k]), "v"(p[8 * c + 2 * k + 1]));
          pk[c][k] = r_;
          sw[c][k] = (unsigned int)__shfl_xor((int)r_, 32, 64);
        }
      bf16x8 pb[2];
      #pragma unroll
      for (int c = 0; c < 2; c++) {
        union { unsigned int u4[4]; bf16x8 v; } bw;
        bw.u4[0] = hi ? sw[c][2] : pk[c][0];
        bw.u4[1] = hi ? sw[c][3] : pk[c][1];
        bw.u4[2] = hi ? pk[c][2] : sw[c][0];
        bw.u4[3] = hi ? pk[c][3] : sw[c][1];
        pb[c] = bw.v;
      }
      #pragma unroll
      for (int vc = 0; vc < 4; vc++) {
        const char* vrow = vb + (vc * 32 + qcol) * 80 + hi * 16;
        bf16x8 va0 = *reinterpret_cast<const bf16x8*>(vrow);
        bf16x8 va1 = *reinterpret_cast<const bf16x8*>(vrow + 32);
        O[vc] = __builtin_amdgcn_mfma_f32_32x32x16_bf16(va0, pb[0], O[vc], 0, 0, 0);
        O[vc] = __builtin_amdgcn_mfma_f32_32x32x16_bf16(va1, pb[1], O[vc], 0, 0, 0);
      }
    }
    if (t + 1 < tend) {
      wr_lds(cur ^ 1);
      if (t + 2 < tend) ld_regs(t + 2);
    }
    asm volatile("s_waitcnt lgkmcnt(0)" ::: "memory");
    __builtin_amdgcn_s_barrier();
    cur ^= 1;
  }

  __syncthreads();                          // everyone done with K/V buffers
  float inv = lrow > 0.0f ? 1.0f / lrow : 0.0f;
  #pragma unroll
  for (int vc = 0; vc < 4; vc++)
    #pragma unroll
    for (int g = 0; g < 4; g++) {
      int v0 = vc * 32 + 8 * g + 4 * hi;
      ushort4 ov;
      ov.x = f2bf(O[vc][4 * g + 0] * inv); ov.y = f2bf(O[vc][4 * g + 1] * inv);
      ov.z = f2bf(O[vc][4 * g + 2] * inv); ov.w = f2bf(O[vc][4 * g + 3] * inv);
      *reinterpret_cast<ushort4*>(lds + (w * 32 + qcol) * 272 + v0 * 2) = ov;
    }
  __syncthreads();
  #pragma unroll
  for (int j = 0; j < 8; j++) {             // each instr: wave covers 1KB contiguous
    int row = w * 32 + j * 4 + (l >> 4);
    uint4 vv = *reinterpret_cast<const uint4*>(lds + row * 272 + (l & 15) * 16);
    *reinterpret_cast<uint4*>(opart + ((size_t)b * 128 + row) * DHEAD + (l & 15) * 8) = vv;
  }
  if (l < 32)
    mlbuf[(size_t)b * 128 + w * 32 + l] = make_float2(mrow, lrow);
}

// ---------- combine up to 7 chunk partials per (h, q-row) ----------
__global__ void k_comb2(const unsigned short* __restrict__ opart,
                        const float2* __restrict__ mlbuf,
                        unsigned short* __restrict__ z) {
  int g = blockIdx.x * 256 + threadIdx.x;     // 16h * 2048q * 16vg
  int vg = g & 15, q = (g >> 4) & 2047, h = g >> 15;
  int qt = q >> 7, r = q & 127;
  int base = 0;
  for (int j = 0; j < qt; j++) base += chunks_of(j);
  const int nc = chunks_of(qt);               // 1..7
  float m = -3.0e38f;
  float2 ml[7];
  #pragma unroll
  for (int cc = 0; cc < 7; cc++)
    if (cc < nc) {
      ml[cc] = mlbuf[(size_t)((base + cc) * 16 + h) * 128 + r];
      m = fmaxf(m, ml[cc].x);
    }
  float wts[7], wsum = 0.0f;
  #pragma unroll
  for (int cc = 0; cc < 7; cc++)
    if (cc < nc) {
      float wv = ml[cc].y > 0.0f ? ml[cc].y * __expf(ml[cc].x - m) : 0.0f;
      wts[cc] = wv; wsum += wv;
    }
  float wi = 1.0f / wsum;
  float acc[8] = {};
  #pragma unroll
  for (int cc = 0; cc < 7; cc++)
    if (cc < nc && wts[cc] > 0.0f) {
      float wv = wts[cc] * wi;
      bf16x8 v = *reinterpret_cast<const bf16x8*>(
          opart + ((size_t)((base + cc) * 16 + h) * 128 + r) * DHEAD + vg * 8);
      #pragma unroll
      for (int j = 0; j < 8; j++) acc[j] += wv * (float)v[j];
    }
  unsigned short* zp = z + (size_t)q * D_MODEL + h * DHEAD + vg * 8;
  ushort4 lo, hi4;
  lo.x = f2bf(acc[0]); lo.y = f2bf(acc[1]); lo.z = f2bf(acc[2]); lo.w = f2bf(acc[3]);
  hi4.x = f2bf(acc[4]); hi4.y = f2bf(acc[5]); hi4.z = f2bf(acc[6]); hi4.w = f2bf(acc[7]);
  *reinterpret_cast<ushort4*>(zp) = lo;
  *reinterpret_cast<ushort4*>(zp + 4) = hi4;
}

// ---------- output GEMM: out(S,D) = z @ obT^T; BM=64 BN=128 BK=64, grid 512 ----------
__global__ __launch_bounds__(256) void k_out2(
    const unsigned short* __restrict__ zb, const unsigned short* __restrict__ obT,
    float* __restrict__ out) {
  __shared__ char lds[49152];               // buf p @ p*24576: A[64][128B] | B[128][128B] @+8K
  const int tid = threadIdx.x, l = tid & 63, w = tid >> 6;
  const int lr = l & 15, lk = l >> 4;
  const int orig = blockIdx.x;
  const int wg = (orig & 7) * 64 + (orig >> 3);   // 512%8==0, bijective
  const int bx = wg & 31, by = wg >> 5;     // s-tile(64), n-tile(128)
  const int s0 = bx * 64, n0 = by * 128;
  const int wm = w >> 1, wn = w & 1;        // wave = 32 rows x 64 cols
  f32x4 acc[2][4] = {};

  auto stage = [&](int t, int buf) {        // 6 gl_lds/thread (2 A + 4 B)
    const int kt = t * 64;
    char* dst = lds + buf * 24576;
    #pragma unroll
    for (int j = 0; j < 2; j++) {           // A: 64 rows x 8 chunks = 512
      int ci = tid + j * 256;
      int r = ci >> 3, c8 = ci & 7;
      int csrc = (c8 ^ (r & 7)) * 8;
      gl_lds16(zb + (size_t)(s0 + r) * D_MODEL + kt + csrc, dst + ci * 16);
    }
    #pragma unroll
    for (int j = 0; j < 4; j++) {           // B: 128 rows x 8 chunks = 1024
      int ci = tid + j * 256;
      int r = ci >> 3, c8 = ci & 7;
      int csrc = (c8 ^ (r & 7)) * 8;
      gl_lds16(obT + (size_t)(n0 + r) * D_MODEL + kt + csrc, dst + 8192 + ci * 16);
    }
  };

  stage(0, 0);
  int cur = 0;
  const int nT = D_MODEL / 64;
  for (int t = 0; t < nT; t++) {
    if (t + 1 < nT) {
      stage(t + 1, cur ^ 1);
      asm volatile("s_waitcnt vmcnt(6)" ::: "memory");
    } else {
      asm volatile("s_waitcnt vmcnt(0)" ::: "memory");
    }
    __builtin_amdgcn_s_barrier();
    const char* base = lds + cur * 24576;
    #pragma unroll
    for (int kk = 0; kk < 2; kk++) {
      const int kb = kk * 64 + lk * 16;
      bf16x8 a[2], b[4];
      #pragma unroll
      for (int mf = 0; mf < 2; mf++) {
        int rr = wm * 32 + mf * 16 + lr;
        a[mf] = *reinterpret_cast<const bf16x8*>(base + rr * 128 + (kb ^ ((rr & 7) << 4)));
      }
      #pragma unroll
      for (int nf = 0; nf < 4; nf++) {
        int rn = wn * 64 + nf * 16 + lr;
        b[nf] = *reinterpret_cast<const bf16x8*>(base + 8192 + rn * 128 + (kb ^ ((rn & 7) << 4)));
      }
      #pragma unroll
      for (int mf = 0; mf < 2; mf++)
        #pragma unroll
        for (int nf = 0; nf < 4; nf++)
          acc[mf][nf] = __builtin_amdgcn_mfma_f32_16x16x32_bf16(a[mf], b[nf], acc[mf][nf], 0, 0, 0);
    }
    asm volatile("s_waitcnt lgkmcnt(0)" ::: "memory");
    __builtin_amdgcn_s_barrier();
    cur ^= 1;
  }
  const float osc = 0.022097086912079608f;      // 1/sqrt(2048)
  #pragma unroll
  for (int mf = 0; mf < 2; mf++)
    #pragma unroll
    for (int nf = 0; nf < 4; nf++)
      #pragma unroll
      for (int rg = 0; rg < 4; rg++)
        out[(size_t)(s0 + wm * 32 + mf * 16 + lk * 4 + rg) * D_MODEL + n0 + wn * 64 + nf * 16 + lr]
            = acc[mf][nf][rg] * osc;
}

extern "C" void kernel_launch(void* const* d_in, const int* in_sizes, int n_in,
                              void* d_out, int out_size, void* d_ws, size_t ws_size,
                              hipStream_t stream) {
  const float* x = (const float*)d_in[0];
  const float* q = (const float*)d_in[1];
  const float* k = (const float*)d_in[2];
  const float* v = (const float*)d_in[3];
  const float* o = (const float*)d_in[4];
  const float* theta = (const float*)d_in[5];
  float* out = (float*)d_out;

  char* ws = (char*)d_ws;
  const size_t MB = 1u << 20;
  unsigned short* xb  = (unsigned short*)(ws + 0 * MB);
  unsigned short* qbT = (unsigned short*)(ws + 8 * MB);   // merged W^T[6144][2048] start
  unsigned short* obT = (unsigned short*)(ws + 32 * MB);
  unsigned short* rq  = (unsigned short*)(ws + 40 * MB);
  unsigned short* rk  = (unsigned short*)(ws + 48 * MB);
  unsigned short* vst = (unsigned short*)(ws + 56 * MB);
  float* sint = (float*)(ws + 64 * MB);
  float* cost = (float*)(ws + 64 * MB + 512 * 1024);
  unsigned short* opart = (unsigned short*)(ws + 0 * MB);   // 976*128*128*2B = 30.5MB
  float2* mlbuf         = (float2*)(ws + 31 * MB);          // 976*128*8B ~ 1MB
  unsigned short* zb    = (unsigned short*)(ws + 40 * MB);  // reuse rq (dead after attn)

  k_prep<<<dim3(20992), dim3(256), 0, stream>>>(x, q, k, v, o, theta, xb, qbT, obT, sint, cost);
  k_proj2<<<dim3(768), dim3(256), 0, stream>>>(xb, qbT, sint, cost, rq, rk, vst);
  k_attn6<<<dim3(976), dim3(256), 0, stream>>>(rq, rk, vst, opart, mlbuf);
  k_comb2<<<dim3(2048), dim3(256), 0, stream>>>(opart, mlbuf, zb);
  k_out2<<<dim3(512), dim3(256), 0, stream>>>(zb, obT, out);
}